// Round 5
// baseline (141.737 us; speedup 1.0000x reference)
//
#include <hip/hip_runtime.h>
#include <stdint.h>
#include <math.h>

using u16    = unsigned short;
using short8 = __attribute__((ext_vector_type(8))) short;
using f32x4  = __attribute__((ext_vector_type(4))) float;
using f32x16 = __attribute__((ext_vector_type(16))) float;
using u32x4  = __attribute__((ext_vector_type(4))) uint32_t;

#define DEVI __device__ __forceinline__
#define FENCE asm volatile("" ::: "memory")
#define GPTR(p) ((const __attribute__((address_space(1))) uint32_t*)(p))
#define LPTR(p) ((__attribute__((address_space(3))) uint32_t*)(p))

static constexpr int S  = 2048;
static constexpr int D  = 512;
static constexpr int DH = 64;
// log2(e)/sqrt(512): folded into the Q projection output
static constexpr float C2 = 0.063763906f;

DEVI u16 f2bf(float f){
  uint32_t u = __float_as_uint(f);
  u = u + 0x7FFFu + ((u >> 16) & 1u);   // RNE
  return (u16)(u >> 16);
}

DEVI uint32_t cvt_pk_bf16(float a, float b){
  uint32_t d;
  asm("v_cvt_pk_bf16_f32 %0, %1, %2" : "=v"(d) : "v"(a), "v"(b));
  return d;
}

// ---------------- weight fp32 -> bf16 ----------------
__global__ void k_cvtw(const float* __restrict__ a, const float* __restrict__ b,
                       const float* __restrict__ c, const float* __restrict__ d,
                       u16* __restrict__ out){
  int i = blockIdx.x * blockDim.x + threadIdx.x;
  int sel = i >> 16;
  const float* src = sel == 0 ? a : sel == 1 ? b : sel == 2 ? c : d;
  float4 v = reinterpret_cast<const float4*>(src)[i & ((1<<16)-1)];
  uint2 o;
  o.x = (uint32_t)f2bf(v.x) | ((uint32_t)f2bf(v.y) << 16);
  o.y = (uint32_t)f2bf(v.z) | ((uint32_t)f2bf(v.w) << 16);
  reinterpret_cast<uint2*>(out)[i] = o;
}

// ---------------- projection GEMM, fused fp32->bf16 A-staging ----------------
// C[m][n] = (sum_k X[m][k]*W[n][k] + bias[n]) * oscale
// 512 thr = 8 waves (4m x 2n), tile 128x64, BK=64. A reg-staged+converted, B gload_lds.
// MODE 0: out bf16 at ((b*8+h)*2048+s)*64+d ; MODE 2: out bf16 ((b*8+h)*64+d)*2048+s
template<int MODE>
__global__ __launch_bounds__(512)
void k_gemm_xw(const float* __restrict__ X, const u16* __restrict__ W,
               const float* __restrict__ bias, u16* __restrict__ outp, float oscale)
{
  __shared__ __align__(16) u16 As[2][128*64];
  __shared__ __align__(16) u16 Bs[2][64*64];
  const int tid = threadIdx.x;
  const int w = tid >> 6, l = tid & 63;
  const int wm = w & 3, wn = w >> 2;
  const int n0 = blockIdx.x * 64, m0 = blockIdx.y * 128;   // n fastest: A-panel L2 reuse
  const int srow = l >> 3, sslot = l & 7;

  f32x4 acc[2][2];
  #pragma unroll
  for (int i = 0; i < 2; i++)
    #pragma unroll
    for (int j = 0; j < 2; j++)
      #pragma unroll
      for (int r = 0; r < 4; r++) acc[i][j][r] = 0.f;

  float4 av[4];
  auto LOADA = [&](int kt){
    #pragma unroll
    for (int j = 0; j < 4; j++){
      int row = j*32 + (tid >> 4), h = tid & 15;
      av[j] = *reinterpret_cast<const float4*>(&X[(long)(m0 + row)*D + kt + h*4]);
    }
  };
  auto WRITEA = [&](int buf){
    #pragma unroll
    for (int j = 0; j < 4; j++){
      int row = j*32 + (tid >> 4), h = tid & 15;
      uint2 pk;
      pk.x = cvt_pk_bf16(av[j].x, av[j].y);
      pk.y = cvt_pk_bf16(av[j].z, av[j].w);
      int slot = (h >> 1) ^ (row & 7);
      *reinterpret_cast<uint2*>(&As[buf][row*64 + slot*8 + (h & 1)*4]) = pk;
    }
  };
  auto STAGEB = [&](int buf, int kt){
    int r = w*8 + srow;
    int scol = (sslot ^ (r & 7)) * 8;
    __builtin_amdgcn_global_load_lds(GPTR(W + (long)(n0 + r)*D + kt + scol),
                                     LPTR(&Bs[buf][(w*8)*64]), 16, 0, 0);
  };

  LOADA(0); STAGEB(0, 0);
  asm volatile("s_waitcnt vmcnt(0)" ::: "memory");
  WRITEA(0);
  __syncthreads();

  for (int t = 0; t < 8; t++){
    int buf = t & 1;
    if (t < 7){ STAGEB(buf ^ 1, (t+1)*64); LOADA((t+1)*64); }
    #pragma unroll
    for (int ks = 0; ks < 2; ks++){
      short8 af[2], bf[2];
      #pragma unroll
      for (int mf = 0; mf < 2; mf++){
        int row = wm*32 + mf*16 + (l & 15);
        int cw = (ks*4 + (l >> 4)) ^ (row & 7);
        af[mf] = *reinterpret_cast<const short8*>(&As[buf][(row*8 + cw)*8]);
      }
      #pragma unroll
      for (int nf = 0; nf < 2; nf++){
        int row = wn*32 + nf*16 + (l & 15);
        int cw = (ks*4 + (l >> 4)) ^ (row & 7);
        bf[nf] = *reinterpret_cast<const short8*>(&Bs[buf][(row*8 + cw)*8]);
      }
      #pragma unroll
      for (int nf = 0; nf < 2; nf++)
        #pragma unroll
        for (int mf = 0; mf < 2; mf++)
          acc[mf][nf] = __builtin_amdgcn_mfma_f32_16x16x32_bf16(af[mf], bf[nf], acc[mf][nf], 0, 0, 0);
    }
    asm volatile("s_waitcnt vmcnt(0)" ::: "memory");
    if (t < 7) WRITEA(buf ^ 1);
    __syncthreads();
  }

  #pragma unroll
  for (int mf = 0; mf < 2; mf++){
    #pragma unroll
    for (int nf = 0; nf < 2; nf++){
      int n = n0 + wn*32 + nf*16 + (l & 15);
      float bi = bias[n];
      int h_ = n >> 6, d_ = n & 63;
      if constexpr (MODE == 2){
        int mb = m0 + wm*32 + mf*16 + (l >> 4)*4;
        int b_ = mb >> 11, s_ = mb & 2047;
        uint2 o;
        o.x = (uint32_t)f2bf((acc[mf][nf][0] + bi)*oscale) | ((uint32_t)f2bf((acc[mf][nf][1] + bi)*oscale) << 16);
        o.y = (uint32_t)f2bf((acc[mf][nf][2] + bi)*oscale) | ((uint32_t)f2bf((acc[mf][nf][3] + bi)*oscale) << 16);
        *reinterpret_cast<uint2*>(&outp[((long)((b_*8 + h_)*64 + d_))*2048 + s_]) = o;
      } else {
        #pragma unroll
        for (int r = 0; r < 4; r++){
          int m = m0 + wm*32 + mf*16 + (l >> 4)*4 + r;
          int b_ = m >> 11, s_ = m & 2047;
          outp[((long)((b_*8 + h_)*2048 + s_))*64 + d_] = f2bf((acc[mf][nf][r] + bi)*oscale);
        }
      }
    }
  }
}

// ---------------- output GEMM: d_out[m][n] = sum_k AO[m][k]*Wo[n][k] + bias2[b][n] ----------------
__global__ __launch_bounds__(512)
void k_gemm_ao(const u16* __restrict__ A, const u16* __restrict__ W,
               const float* __restrict__ bias2, float* __restrict__ outp)
{
  __shared__ __align__(16) u16 As[2][128*64];
  __shared__ __align__(16) u16 Bs[2][64*64];
  const int tid = threadIdx.x;
  const int w = tid >> 6, l = tid & 63;
  const int wm = w & 3, wn = w >> 2;
  const int n0 = blockIdx.x * 64, m0 = blockIdx.y * 128;
  const int srow = l >> 3, sslot = l & 7;

  f32x4 acc[2][2];
  #pragma unroll
  for (int i = 0; i < 2; i++)
    #pragma unroll
    for (int j = 0; j < 2; j++)
      #pragma unroll
      for (int r = 0; r < 4; r++) acc[i][j][r] = 0.f;

  auto STAGE = [&](int buf, int kt){
    #pragma unroll
    for (int i = 0; i < 2; i++){
      int r = w*16 + i*8 + srow;
      int scol = (sslot ^ (r & 7)) * 8;
      int m = m0 + r, k = kt + scol;
      long ga = ((long)(((m >> 11)*8 + (k >> 6))*2048 + (m & 2047)))*64 + (k & 63);
      __builtin_amdgcn_global_load_lds(GPTR(A + ga), LPTR(&As[buf][(w*16 + i*8)*64]), 16, 0, 0);
    }
    int r = w*8 + srow;
    int scol = (sslot ^ (r & 7)) * 8;
    __builtin_amdgcn_global_load_lds(GPTR(W + (long)(n0 + r)*D + kt + scol),
                                     LPTR(&Bs[buf][(w*8)*64]), 16, 0, 0);
  };

  STAGE(0, 0);
  asm volatile("s_waitcnt vmcnt(0)" ::: "memory");
  __builtin_amdgcn_s_barrier();
  FENCE;

  for (int t = 0; t < 8; t++){
    int buf = t & 1;
    if (t < 7) STAGE(buf ^ 1, (t+1)*64);
    #pragma unroll
    for (int ks = 0; ks < 2; ks++){
      short8 af[2], bf[2];
      #pragma unroll
      for (int mf = 0; mf < 2; mf++){
        int row = wm*32 + mf*16 + (l & 15);
        int cw = (ks*4 + (l >> 4)) ^ (row & 7);
        af[mf] = *reinterpret_cast<const short8*>(&As[buf][(row*8 + cw)*8]);
      }
      #pragma unroll
      for (int nf = 0; nf < 2; nf++){
        int row = wn*32 + nf*16 + (l & 15);
        int cw = (ks*4 + (l >> 4)) ^ (row & 7);
        bf[nf] = *reinterpret_cast<const short8*>(&Bs[buf][(row*8 + cw)*8]);
      }
      #pragma unroll
      for (int nf = 0; nf < 2; nf++)
        #pragma unroll
        for (int mf = 0; mf < 2; mf++)
          acc[mf][nf] = __builtin_amdgcn_mfma_f32_16x16x32_bf16(af[mf], bf[nf], acc[mf][nf], 0, 0, 0);
    }
    asm volatile("s_waitcnt vmcnt(0)" ::: "memory");
    __builtin_amdgcn_s_barrier();
    FENCE;
  }

  #pragma unroll
  for (int mf = 0; mf < 2; mf++)
    #pragma unroll
    for (int nf = 0; nf < 2; nf++){
      int n = n0 + wn*32 + nf*16 + (l & 15);
      float bi = bias2[(m0 >> 11)*512 + n];
      #pragma unroll
      for (int r = 0; r < 4; r++){
        int m = m0 + wm*32 + mf*16 + (l >> 4)*4 + r;
        outp[(long)m*D + n] = acc[mf][nf][r] + bi;
      }
    }
}

// ---------------- SV[bh][d] = sum_t Vt[bh][d][t] ----------------
__global__ __launch_bounds__(256)
void k_sumv(const u16* __restrict__ Vt, float* __restrict__ SV){
  const int w = threadIdx.x >> 6, l = threadIdx.x & 63;
  const int row = blockIdx.x*4 + w;
  const u16* src = Vt + (long)row * S;
  float s = 0.f;
  #pragma unroll
  for (int j = 0; j < 4; j++){
    short8 v = *reinterpret_cast<const short8*>(&src[j*512 + l*8]);
    #pragma unroll
    for (int e = 0; e < 8; e++)
      s += __uint_as_float(((uint32_t)(u16)v[e]) << 16);
  }
  #pragma unroll
  for (int m = 1; m < 64; m <<= 1) s += __shfl_xor(s, m, 64);
  if (l == 0) SV[row] = s;
}

// ---------------- bias2[b][n] = bo[n] + 0.5 * sum_k SV[b][k]*Wo[n][k] ----------------
__global__ __launch_bounds__(256)
void k_bias2(const float* __restrict__ SV, const float* __restrict__ Wo,
             const float* __restrict__ bo, float* __restrict__ bias2){
  const int w = threadIdx.x >> 6, l = threadIdx.x & 63;
  const int idx = blockIdx.x*4 + w;
  const int b = idx >> 9, n = idx & 511;
  float dot = 0.f;
  #pragma unroll
  for (int j = 0; j < 2; j++){
    float4 wv = *reinterpret_cast<const float4*>(&Wo[(long)n*512 + l*8 + j*4]);
    float4 sv = *reinterpret_cast<const float4*>(&SV[b*512 + l*8 + j*4]);
    dot += wv.x*sv.x + wv.y*sv.y + wv.z*sv.z + wv.w*sv.w;
  }
  #pragma unroll
  for (int m = 1; m < 64; m <<= 1) dot += __shfl_xor(dot, m, 64);
  if (l == 0) bias2[idx] = bo[n] + 0.5f * dot;
}

// ---------------- flash, 8 waves: groups 0/1 split even/odd K-tiles ----------------
// AO = 0.25 * softmax(K.(Q*C2)) V ; in-register P via cvt_pk + permlane32_swap
__global__ __launch_bounds__(512)
void k_flash(const u16* __restrict__ Qp, const u16* __restrict__ Kp,
             const u16* __restrict__ Vt, u16* __restrict__ AO)
{
  __shared__ __align__(16) u16 Ks[2][2][64*64];   // [group][buf]
  __shared__ __align__(16) u16 Vs[2][2][64*64];
  const int tid = threadIdx.x, w = tid >> 6, l = tid & 63;
  const int g = w >> 2, w4 = w & 3;
  const int bh = blockIdx.x & 31, qt = blockIdx.x >> 5;
  const u16* Qb = Qp + (long)bh * S * DH;
  const u16* Kb = Kp + (long)bh * S * DH;
  const u16* Vb = Vt + (long)bh * DH * S;
  const int hi = l >> 5, ln = l & 31;
  const int srow = l >> 3, sslot = l & 7;

  short8 qfr[4];   // Q*C2 (scale folded in projection)
  #pragma unroll
  for (int c = 0; c < 4; c++){
    int row = qt*128 + w4*32 + ln;
    qfr[c] = *reinterpret_cast<const short8*>(&Qb[(long)row*DH + c*16 + hi*8]);
  }

  auto STAGE = [&](int buf, int t){
    int kt = t*2 + g;
    #pragma unroll
    for (int i = 0; i < 2; i++){
      int r = w4*16 + i*8 + srow;
      int scol = (sslot ^ (r & 7)) * 8;
      __builtin_amdgcn_global_load_lds(GPTR(Kb + (long)(kt*64 + r)*DH + scol),
                                       LPTR(&Ks[g][buf][(w4*16 + i*8)*64]), 16, 0, 0);
      __builtin_amdgcn_global_load_lds(GPTR(Vb + (long)r*S + kt*64 + scol),
                                       LPTR(&Vs[g][buf][(w4*16 + i*8)*64]), 16, 0, 0);
    }
  };

  f32x16 oacc[2];
  #pragma unroll
  for (int j = 0; j < 2; j++)
    #pragma unroll
    for (int r = 0; r < 16; r++) oacc[j][r] = 0.f;
  float lsum = 0.f;

  STAGE(0, 0);
  asm volatile("s_waitcnt vmcnt(0)" ::: "memory");
  __builtin_amdgcn_s_barrier();
  FENCE;

  for (int t = 0; t < 16; t++){
    int buf = t & 1;
    if (t + 1 < 16) STAGE(buf ^ 1, t + 1);
    #pragma unroll
    for (int kf = 0; kf < 2; kf++){
      f32x16 sacc;
      #pragma unroll
      for (int r = 0; r < 16; r++) sacc[r] = 0.f;
      #pragma unroll
      for (int c = 0; c < 4; c++){
        int key = kf*32 + ln;
        int slot = (c*2 + hi) ^ (key & 7);
        short8 kfrag = *reinterpret_cast<const short8*>(&Ks[g][buf][key*64 + slot*8]);
        sacc = __builtin_amdgcn_mfma_f32_32x32x16_bf16(kfrag, qfr[c], sacc, 0, 0, 0);
      }
      float e[16];
      #pragma unroll
      for (int r = 0; r < 16; r++) e[r] = __builtin_amdgcn_exp2f(sacc[r]);
      #pragma unroll
      for (int r = 0; r < 16; r += 4) lsum += (e[r] + e[r+1]) + (e[r+2] + e[r+3]);
      uint32_t pk[8];
      #pragma unroll
      for (int j = 0; j < 8; j++) pk[j] = cvt_pk_bf16(e[2*j], e[2*j+1]);
      #pragma unroll
      for (int ch = 0; ch < 2; ch++){
        auto s1 = __builtin_amdgcn_permlane32_swap(pk[ch*4+0], pk[ch*4+2], false, false);
        auto s2 = __builtin_amdgcn_permlane32_swap(pk[ch*4+1], pk[ch*4+3], false, false);
        u32x4 av = { (uint32_t)s1[0], (uint32_t)s2[0], (uint32_t)s1[1], (uint32_t)s2[1] };
        short8 af = __builtin_bit_cast(short8, av);
        int k0 = kf*32 + ch*16;
        #pragma unroll
        for (int nf = 0; nf < 2; nf++){
          int d = nf*32 + ln;
          int slot = ((k0 >> 3) + hi) ^ (d & 7);
          short8 vfrag = *reinterpret_cast<const short8*>(&Vs[g][buf][d*64 + slot*8]);
          oacc[nf] = __builtin_amdgcn_mfma_f32_32x32x16_bf16(af, vfrag, oacc[nf], 0, 0, 0);
        }
      }
    }
    asm volatile("s_waitcnt vmcnt(0)" ::: "memory");
    __builtin_amdgcn_s_barrier();
    FENCE;
  }

  // cross-group combine in LDS (tiles are done; reuse Ks as 32KB f32 buffer)
  lsum += __shfl_xor(lsum, 32, 64);
  float* OB = (float*)Ks;    // 4 waves x 32 qrow x 64 d = 8192 f32 = 32 KB
  float* LB = (float*)Vs;    // 4 x 32 f32
  if (g == 1){
    #pragma unroll
    for (int r = 0; r < 16; r++){
      int qrow = (r & 3) + 8*(r >> 2) + 4*hi;
      #pragma unroll
      for (int nf = 0; nf < 2; nf++)
        OB[w4*2048 + qrow*64 + nf*32 + ln] = oacc[nf][r];
    }
    if (hi == 0) LB[w4*32 + ln] = lsum;
  }
  __syncthreads();
  if (g == 0){
    float l2 = LB[w4*32 + ln];
    float linv = 0.25f / (lsum + l2);   // valid for qrow = ln
    #pragma unroll
    for (int r = 0; r < 16; r++){
      int qrow = (r & 3) + 8*(r >> 2) + 4*hi;
      float sc = __shfl(linv, qrow, 64);
      int s_ = qt*128 + w4*32 + qrow;
      #pragma unroll
      for (int nf = 0; nf < 2; nf++){
        float o = oacc[nf][r] + OB[w4*2048 + qrow*64 + nf*32 + ln];
        AO[((long)bh*S + s_)*DH + nf*32 + ln] = f2bf(o * sc);
      }
    }
  }
}

// ---------------- launch ----------------
extern "C" void kernel_launch(void* const* d_in, const int* in_sizes, int n_in,
                              void* d_out, int out_size, void* d_ws, size_t ws_size,
                              hipStream_t stream)
{
  const float* query = (const float*)d_in[0];
  const float* key_  = (const float*)d_in[1];
  const float* value = (const float*)d_in[2];
  const float* Wq = (const float*)d_in[3];
  const float* bq = (const float*)d_in[4];
  const float* Wk = (const float*)d_in[5];
  const float* bk = (const float*)d_in[6];
  const float* Wv = (const float*)d_in[7];
  const float* bv = (const float*)d_in[8];
  const float* Wo = (const float*)d_in[9];
  const float* bo = (const float*)d_in[10];

  char* ws = (char*)d_ws;
  const size_t XSZ = (size_t)8192 * 512 * 2;   // 8 MiB
  const size_t WSZ = (size_t)512 * 512 * 2;    // 512 KiB
  u16* AO  = (u16*)(ws);
  u16* wqb = (u16*)(ws + XSZ);
  u16* wkb = (u16*)(ws + XSZ + WSZ);
  u16* wvb = (u16*)(ws + XSZ + 2*WSZ);
  u16* wob = (u16*)(ws + XSZ + 3*WSZ);
  u16* Qp  = (u16*)(ws + XSZ + 4*WSZ);
  u16* Kp  = (u16*)(ws + 2*XSZ + 4*WSZ);
  u16* Vtp = (u16*)(ws + 3*XSZ + 4*WSZ);
  float* SV    = (float*)(ws + 4*XSZ + 4*WSZ);
  float* bias2 = (float*)(ws + 4*XSZ + 4*WSZ + 8192);

  k_cvtw<<<(4<<16)/256, 256, 0, stream>>>(Wq, Wk, Wv, Wo, wqb);

  dim3 gx(8, 64);  // n fastest: blocks sharing an A-panel co-schedule
  k_gemm_xw<0><<<gx, 512, 0, stream>>>(query, wqb, bq, Qp, C2);
  k_gemm_xw<0><<<gx, 512, 0, stream>>>(key_,  wkb, bk, Kp, 1.0f);
  k_gemm_xw<2><<<gx, 512, 0, stream>>>(value, wvb, bv, Vtp, 1.0f);

  k_sumv <<<512, 256, 0, stream>>>(Vtp, SV);
  k_bias2<<<512, 256, 0, stream>>>(SV, Wo, bo, bias2);

  k_flash<<<512, 512, 0, stream>>>(Qp, Kp, Vtp, AO);

  k_gemm_ao<<<gx, 512, 0, stream>>>(AO, wob, bias2, (float*)d_out);
}

// Round 6
// 110.125 us; speedup vs baseline: 1.2871x; 1.2871x over previous
//
#include <hip/hip_runtime.h>
#include <stdint.h>
#include <math.h>

using u16    = unsigned short;
using short8 = __attribute__((ext_vector_type(8))) short;
using f32x4  = __attribute__((ext_vector_type(4))) float;
using f32x16 = __attribute__((ext_vector_type(16))) float;
using u32x4  = __attribute__((ext_vector_type(4))) uint32_t;

#define DEVI __device__ __forceinline__
#define FENCE asm volatile("" ::: "memory")
#define GPTR(p) ((const __attribute__((address_space(1))) uint32_t*)(p))
#define LPTR(p) ((__attribute__((address_space(3))) uint32_t*)(p))

static constexpr int S  = 2048;
static constexpr int D  = 512;
static constexpr int DH = 64;
// log2(e)/sqrt(512): folded into the Q projection output
static constexpr float C2 = 0.063763906f;

DEVI u16 f2bf(float f){
  uint32_t u = __float_as_uint(f);
  u = u + 0x7FFFu + ((u >> 16) & 1u);   // RNE
  return (u16)(u >> 16);
}

DEVI uint32_t cvt_pk_bf16(float a, float b){
  uint32_t d;
  asm("v_cvt_pk_bf16_f32 %0, %1, %2" : "=v"(d) : "v"(a), "v"(b));
  return d;
}

// ---------------- fused fp32 -> bf16 converts ----------------
__global__ void k_cvt3(const float* __restrict__ a, const float* __restrict__ b,
                       const float* __restrict__ c, u16* __restrict__ out){
  int i = blockIdx.x * blockDim.x + threadIdx.x;
  const float* src = (i < (1<<20)) ? a : (i < (2<<20) ? b : c);
  float4 v = reinterpret_cast<const float4*>(src)[i & ((1<<20)-1)];
  uint2 o;
  o.x = (uint32_t)f2bf(v.x) | ((uint32_t)f2bf(v.y) << 16);
  o.y = (uint32_t)f2bf(v.z) | ((uint32_t)f2bf(v.w) << 16);
  reinterpret_cast<uint2*>(out)[i] = o;
}

__global__ void k_cvtw(const float* __restrict__ a, const float* __restrict__ b,
                       const float* __restrict__ c, const float* __restrict__ d,
                       u16* __restrict__ out){
  int i = blockIdx.x * blockDim.x + threadIdx.x;
  int sel = i >> 16;
  const float* src = sel == 0 ? a : sel == 1 ? b : sel == 2 ? c : d;
  float4 v = reinterpret_cast<const float4*>(src)[i & ((1<<16)-1)];
  uint2 o;
  o.x = (uint32_t)f2bf(v.x) | ((uint32_t)f2bf(v.y) << 16);
  o.y = (uint32_t)f2bf(v.z) | ((uint32_t)f2bf(v.w) << 16);
  reinterpret_cast<uint2*>(out)[i] = o;
}

// ---------------- GEMM: C[m][n] = (sum_k A[m][k]*W[n][k] + bias)*oscale ----------------
// 512 threads = 8 waves (4m x 2n), tile 128x128, BK=64, gload_lds dbuf.  (round-3 proven)
// MODE 0: out bf16 ((b*8+h)*2048+s)*64+d ; MODE 2: out bf16 ((b*8+h)*64+d)*2048+s
// MODE 3: A head-interleaved bf16, bias=bias2[b][n], out fp32 row-major
template<int MODE>
__global__ __launch_bounds__(512)
void k_gemm_bt(const u16* __restrict__ A, const u16* __restrict__ W,
               const float* __restrict__ bias, void* __restrict__ outp, float oscale)
{
  __shared__ __align__(16) u16 As[2][128*64];
  __shared__ __align__(16) u16 Bs[2][128*64];
  const int tid = threadIdx.x;
  const int w = tid >> 6, l = tid & 63;
  const int wm = w & 3, wn = w >> 2;
  const int m0 = blockIdx.x * 128, n0 = blockIdx.y * 128;
  const int srow = l >> 3, sslot = l & 7;

  f32x4 acc[2][4];
  #pragma unroll
  for (int i = 0; i < 2; i++)
    #pragma unroll
    for (int j = 0; j < 4; j++)
      #pragma unroll
      for (int r = 0; r < 4; r++) acc[i][j][r] = 0.f;

  auto STAGE = [&](int buf, int kt){
    #pragma unroll
    for (int i = 0; i < 2; i++){
      int r = w*16 + i*8 + srow;
      int scol = (sslot ^ (r & 7)) * 8;
      long ga;
      if constexpr (MODE == 3){
        int m = m0 + r, k = kt + scol;
        ga = ((long)(((m >> 11)*8 + (k >> 6))*2048 + (m & 2047)))*64 + (k & 63);
      } else {
        ga = (long)(m0 + r)*D + kt + scol;
      }
      __builtin_amdgcn_global_load_lds(GPTR(A + ga), LPTR(&As[buf][(w*16 + i*8)*64]), 16, 0, 0);
      long gb = (long)(n0 + r)*D + kt + scol;
      __builtin_amdgcn_global_load_lds(GPTR(W + gb), LPTR(&Bs[buf][(w*16 + i*8)*64]), 16, 0, 0);
    }
  };

  STAGE(0, 0);
  asm volatile("s_waitcnt vmcnt(0)" ::: "memory");
  __builtin_amdgcn_s_barrier();
  FENCE;

  for (int kt = 0; kt < D; kt += 64){
    int buf = (kt >> 6) & 1;
    if (kt + 64 < D) STAGE(buf ^ 1, kt + 64);
    #pragma unroll
    for (int ks = 0; ks < 2; ks++){
      short8 af[2];
      #pragma unroll
      for (int mf = 0; mf < 2; mf++){
        int row = wm*32 + mf*16 + (l & 15);
        int cw = (ks*4 + (l >> 4)) ^ (row & 7);
        af[mf] = *reinterpret_cast<const short8*>(&As[buf][(row*8 + cw)*8]);
      }
      #pragma unroll
      for (int nf = 0; nf < 4; nf++){
        int row = wn*64 + nf*16 + (l & 15);
        int cw = (ks*4 + (l >> 4)) ^ (row & 7);
        short8 bf = *reinterpret_cast<const short8*>(&Bs[buf][(row*8 + cw)*8]);
        #pragma unroll
        for (int mf = 0; mf < 2; mf++)
          acc[mf][nf] = __builtin_amdgcn_mfma_f32_16x16x32_bf16(af[mf], bf, acc[mf][nf], 0, 0, 0);
      }
    }
    asm volatile("s_waitcnt vmcnt(0)" ::: "memory");
    __builtin_amdgcn_s_barrier();
    FENCE;
  }

  #pragma unroll
  for (int mf = 0; mf < 2; mf++){
    #pragma unroll
    for (int nf = 0; nf < 4; nf++){
      int n = n0 + wn*64 + nf*16 + (l & 15);
      float bi;
      if constexpr (MODE == 3) bi = bias[(m0 >> 11)*512 + n];
      else                     bi = bias[n];
      if constexpr (MODE == 2){
        int mb = m0 + wm*32 + mf*16 + (l >> 4)*4;
        int b_ = mb >> 11, s_ = mb & 2047;
        int h_ = n >> 6, d_ = n & 63;
        uint2 o;
        o.x = (uint32_t)f2bf((acc[mf][nf][0] + bi)*oscale) | ((uint32_t)f2bf((acc[mf][nf][1] + bi)*oscale) << 16);
        o.y = (uint32_t)f2bf((acc[mf][nf][2] + bi)*oscale) | ((uint32_t)f2bf((acc[mf][nf][3] + bi)*oscale) << 16);
        *reinterpret_cast<uint2*>(&((u16*)outp)[((long)((b_*8 + h_)*64 + d_))*2048 + s_]) = o;
      } else {
        #pragma unroll
        for (int r = 0; r < 4; r++){
          int m = m0 + wm*32 + mf*16 + (l >> 4)*4 + r;
          float v = (acc[mf][nf][r] + bi)*oscale;
          if constexpr (MODE == 3){
            ((float*)outp)[(long)m*D + n] = v;
          } else {
            int b_ = m >> 11, s_ = m & 2047;
            int h_ = n >> 6, d_ = n & 63;
            ((u16*)outp)[((long)((b_*8 + h_)*2048 + s_))*64 + d_] = f2bf(v);
          }
        }
      }
    }
  }
}

// ---------------- SV[bh][d] = sum_t Vt[bh][d][t] ----------------
__global__ __launch_bounds__(256)
void k_sumv(const u16* __restrict__ Vt, float* __restrict__ SV){
  const int w = threadIdx.x >> 6, l = threadIdx.x & 63;
  const int row = blockIdx.x*4 + w;
  const u16* src = Vt + (long)row * S;
  float s = 0.f;
  #pragma unroll
  for (int j = 0; j < 4; j++){
    short8 v = *reinterpret_cast<const short8*>(&src[j*512 + l*8]);
    #pragma unroll
    for (int e = 0; e < 8; e++)
      s += __uint_as_float(((uint32_t)(u16)v[e]) << 16);
  }
  #pragma unroll
  for (int m = 1; m < 64; m <<= 1) s += __shfl_xor(s, m, 64);
  if (l == 0) SV[row] = s;
}

// ---------------- bias2[b][n] = bo[n] + 0.5 * sum_k SV[b][k]*Wo[n][k] ----------------
__global__ __launch_bounds__(256)
void k_bias2(const float* __restrict__ SV, const float* __restrict__ Wo,
             const float* __restrict__ bo, float* __restrict__ bias2){
  const int w = threadIdx.x >> 6, l = threadIdx.x & 63;
  const int idx = blockIdx.x*4 + w;
  const int b = idx >> 9, n = idx & 511;
  float dot = 0.f;
  #pragma unroll
  for (int j = 0; j < 2; j++){
    float4 wv = *reinterpret_cast<const float4*>(&Wo[(long)n*512 + l*8 + j*4]);
    float4 sv = *reinterpret_cast<const float4*>(&SV[b*512 + l*8 + j*4]);
    dot += wv.x*sv.x + wv.y*sv.y + wv.z*sv.z + wv.w*sv.w;
  }
  #pragma unroll
  for (int m = 1; m < 64; m <<= 1) dot += __shfl_xor(dot, m, 64);
  if (l == 0) bias2[idx] = bo[n] + 0.5f * dot;
}

// ---------------- flash, 8 waves: groups 0/1 split even/odd K-tiles ----------------
// AO = 0.25 * softmax(K.(Q*C2)) V ; in-register P via cvt_pk + permlane32_swap
// All LDS addressing hoisted to lane-constant registers; t-loop unrolled x2 so
// buf/kf fold into ds_read offset immediates.
__global__ __launch_bounds__(512, 4)
void k_flash(const u16* __restrict__ Qp, const u16* __restrict__ Kp,
             const u16* __restrict__ Vt, u16* __restrict__ AO)
{
  __shared__ __align__(16) u16 Ks[2][2][64*64];   // [group][buf]
  __shared__ __align__(16) u16 Vs[2][2][64*64];
  const int tid = threadIdx.x, w = tid >> 6, l = tid & 63;
  const int g = w >> 2, w4 = w & 3;
  const int bh = blockIdx.x & 31, qt = blockIdx.x >> 5;
  const u16* Qb = Qp + (long)bh * S * DH;
  const int hi = l >> 5, ln = l & 31;
  const int srow = l >> 3, sslot = l & 7;

  short8 qfr[4];   // Q*C2 (scale folded in projection)
  #pragma unroll
  for (int c = 0; c < 4; c++){
    int row = qt*128 + w4*32 + ln;
    qfr[c] = *reinterpret_cast<const short8*>(&Qb[(long)row*DH + c*16 + hi*8]);
  }

  // lane-constant LDS read offsets (u16 units within Ks[g]/Vs[g])
  int koff[4], voff[8];
  #pragma unroll
  for (int c = 0; c < 4; c++)
    koff[c] = ln*64 + (((2*c + hi) ^ (ln & 7))*8);
  #pragma unroll
  for (int kf = 0; kf < 2; kf++)
    #pragma unroll
    for (int ch = 0; ch < 2; ch++)
      #pragma unroll
      for (int nf = 0; nf < 2; nf++)
        voff[kf*4 + ch*2 + nf] = (nf*32 + ln)*64 + ((((4*kf + 2*ch) + hi) ^ (ln & 7))*8);

  // staging pointers (advance per tile) + lane-constant source offsets
  const u16* kptr = Kp + (long)bh*S*DH + g*4096;
  const u16* vptr = Vt + (long)bh*DH*S + g*64;
  long ksrc[2], vsrc[2];
  #pragma unroll
  for (int i = 0; i < 2; i++){
    int r = w4*16 + i*8 + srow;
    int sc = (sslot ^ (r & 7))*8;
    ksrc[i] = (long)r*64 + sc;
    vsrc[i] = (long)r*S + sc;
  }

  auto STAGE = [&](int buf){
    #pragma unroll
    for (int i = 0; i < 2; i++){
      __builtin_amdgcn_global_load_lds(GPTR(kptr + ksrc[i]), LPTR(&Ks[g][buf][(w4*16 + i*8)*64]), 16, 0, 0);
      __builtin_amdgcn_global_load_lds(GPTR(vptr + vsrc[i]), LPTR(&Vs[g][buf][(w4*16 + i*8)*64]), 16, 0, 0);
    }
    kptr += 8192;   // 2 K-tiles (g-split stride)
    vptr += 128;    // 2 V-tiles of 64 cols
  };

  f32x16 oacc[2];
  #pragma unroll
  for (int j = 0; j < 2; j++)
    #pragma unroll
    for (int r = 0; r < 16; r++) oacc[j][r] = 0.f;
  float lsum = 0.f;

  STAGE(0);
  asm volatile("s_waitcnt vmcnt(0)" ::: "memory");
  __builtin_amdgcn_s_barrier();
  FENCE;

  const u16* KB = &Ks[g][0][0];
  const u16* VB = &Vs[g][0][0];

  for (int tp = 0; tp < 8; tp++){
    #pragma unroll
    for (int tt = 0; tt < 2; tt++){
      int t = tp*2 + tt;
      if (t < 15) STAGE(tt ^ 1);
      #pragma unroll
      for (int kf = 0; kf < 2; kf++){
        f32x16 sacc;
        #pragma unroll
        for (int r = 0; r < 16; r++) sacc[r] = 0.f;
        #pragma unroll
        for (int c = 0; c < 4; c++){
          short8 kfrag = *reinterpret_cast<const short8*>(KB + koff[c] + tt*4096 + kf*2048);
          sacc = __builtin_amdgcn_mfma_f32_32x32x16_bf16(kfrag, qfr[c], sacc, 0, 0, 0);
        }
        uint32_t pk[8];
        #pragma unroll
        for (int j = 0; j < 8; j++){
          float e0 = __builtin_amdgcn_exp2f(sacc[2*j]);
          float e1 = __builtin_amdgcn_exp2f(sacc[2*j+1]);
          lsum += e0 + e1;
          pk[j] = cvt_pk_bf16(e0, e1);
        }
        #pragma unroll
        for (int ch = 0; ch < 2; ch++){
          auto s1 = __builtin_amdgcn_permlane32_swap(pk[ch*4+0], pk[ch*4+2], false, false);
          auto s2 = __builtin_amdgcn_permlane32_swap(pk[ch*4+1], pk[ch*4+3], false, false);
          u32x4 av = { (uint32_t)s1[0], (uint32_t)s2[0], (uint32_t)s1[1], (uint32_t)s2[1] };
          short8 af = __builtin_bit_cast(short8, av);
          #pragma unroll
          for (int nf = 0; nf < 2; nf++){
            short8 vfrag = *reinterpret_cast<const short8*>(VB + voff[kf*4 + ch*2 + nf] + tt*4096);
            oacc[nf] = __builtin_amdgcn_mfma_f32_32x32x16_bf16(af, vfrag, oacc[nf], 0, 0, 0);
          }
        }
      }
      asm volatile("s_waitcnt vmcnt(0)" ::: "memory");
      __builtin_amdgcn_s_barrier();
      FENCE;
    }
  }

  // cross-group combine in LDS (tiles done; reuse Ks as 32KB f32 buffer)
  lsum += __shfl_xor(lsum, 32, 64);
  float* OB = (float*)Ks;
  float* LB = (float*)Vs;
  if (g == 1){
    #pragma unroll
    for (int r = 0; r < 16; r++){
      int qrow = (r & 3) + 8*(r >> 2) + 4*hi;
      #pragma unroll
      for (int nf = 0; nf < 2; nf++)
        OB[w4*2048 + qrow*64 + nf*32 + ln] = oacc[nf][r];
    }
    if (hi == 0) LB[w4*32 + ln] = lsum;
  }
  __syncthreads();
  if (g == 0){
    float l2 = LB[w4*32 + ln];
    float linv = 0.25f / (lsum + l2);   // valid for qrow = ln
    #pragma unroll
    for (int r = 0; r < 16; r++){
      int qrow = (r & 3) + 8*(r >> 2) + 4*hi;
      float sc = __shfl(linv, qrow, 64);
      int s_ = qt*128 + w4*32 + qrow;
      #pragma unroll
      for (int nf = 0; nf < 2; nf++){
        float o = oacc[nf][r] + OB[w4*2048 + qrow*64 + nf*32 + ln];
        AO[((long)bh*S + s_)*DH + nf*32 + ln] = f2bf(o * sc);
      }
    }
  }
}

// ---------------- launch ----------------
extern "C" void kernel_launch(void* const* d_in, const int* in_sizes, int n_in,
                              void* d_out, int out_size, void* d_ws, size_t ws_size,
                              hipStream_t stream)
{
  const float* query = (const float*)d_in[0];
  const float* key_  = (const float*)d_in[1];
  const float* value = (const float*)d_in[2];
  const float* Wq = (const float*)d_in[3];
  const float* bq = (const float*)d_in[4];
  const float* Wk = (const float*)d_in[5];
  const float* bk = (const float*)d_in[6];
  const float* Wv = (const float*)d_in[7];
  const float* bv = (const float*)d_in[8];
  const float* Wo = (const float*)d_in[9];
  const float* bo = (const float*)d_in[10];

  char* ws = (char*)d_ws;
  const size_t XSZ = (size_t)8192 * 512 * 2;   // 8 MiB
  const size_t WSZ = (size_t)512 * 512 * 2;    // 512 KiB
  u16* xq  = (u16*)(ws);
  u16* xk  = (u16*)(ws + XSZ);
  u16* xv  = (u16*)(ws + 2*XSZ);
  u16* wqb = (u16*)(ws + 3*XSZ);
  u16* wkb = (u16*)(ws + 3*XSZ + WSZ);
  u16* wvb = (u16*)(ws + 3*XSZ + 2*WSZ);
  u16* wob = (u16*)(ws + 3*XSZ + 3*WSZ);
  u16* Qp  = (u16*)(ws + 3*XSZ + 4*WSZ);
  u16* Kp  = (u16*)(ws + 4*XSZ + 4*WSZ);
  u16* Vtp = (u16*)(ws + 5*XSZ + 4*WSZ);
  float* SV    = (float*)(ws + 6*XSZ + 4*WSZ);
  float* bias2 = (float*)(ws + 6*XSZ + 4*WSZ + 8192);
  u16* AO = xq;   // xq dead after Q projection

  k_cvt3<<<(3<<20)/256, 256, 0, stream>>>(query, key_, value, xq);
  k_cvtw<<<(4<<16)/256, 256, 0, stream>>>(Wq, Wk, Wv, Wo, wqb);

  dim3 gg(64, 4), bb(512);
  k_gemm_bt<0><<<gg, bb, 0, stream>>>(xq, wqb, bq, (void*)Qp, C2);
  k_gemm_bt<0><<<gg, bb, 0, stream>>>(xk, wkb, bk, (void*)Kp, 1.0f);
  k_gemm_bt<2><<<gg, bb, 0, stream>>>(xv, wvb, bv, (void*)Vtp, 1.0f);

  k_sumv <<<512, 256, 0, stream>>>(Vtp, SV);
  k_bias2<<<512, 256, 0, stream>>>(SV, Wo, bo, bias2);

  k_flash<<<512, 512, 0, stream>>>(Qp, Kp, Vtp, AO);

  k_gemm_bt<3><<<gg, bb, 0, stream>>>(AO, wob, bias2, d_out, 1.0f);
}

// Round 7
// 98.217 us; speedup vs baseline: 1.4431x; 1.1212x over previous
//
#include <hip/hip_runtime.h>
#include <stdint.h>
#include <math.h>

using u16    = unsigned short;
using short8 = __attribute__((ext_vector_type(8))) short;
using f32x4  = __attribute__((ext_vector_type(4))) float;
using f32x16 = __attribute__((ext_vector_type(16))) float;
using u32x4  = __attribute__((ext_vector_type(4))) uint32_t;

#define DEVI __device__ __forceinline__
#define FENCE asm volatile("" ::: "memory")
#define GPTR(p) ((const __attribute__((address_space(1))) uint32_t*)(p))
#define LPTR(p) ((__attribute__((address_space(3))) uint32_t*)(p))

static constexpr int S  = 2048;
static constexpr int D  = 512;
static constexpr int DH = 64;
// log2(e)/sqrt(512): folded into the Q projection output
static constexpr float C2 = 0.063763906f;

DEVI u16 f2bf(float f){
  uint32_t u = __float_as_uint(f);
  u = u + 0x7FFFu + ((u >> 16) & 1u);   // RNE
  return (u16)(u >> 16);
}

DEVI uint32_t cvt_pk_bf16(float a, float b){
  uint32_t d;
  asm("v_cvt_pk_bf16_f32 %0, %1, %2" : "=v"(d) : "v"(a), "v"(b));
  return d;
}

// ---------------- weight fp32 -> bf16 (wq|wk|wv|wo contiguous) ----------------
__global__ void k_cvtw(const float* __restrict__ a, const float* __restrict__ b,
                       const float* __restrict__ c, const float* __restrict__ d,
                       u16* __restrict__ out){
  int i = blockIdx.x * blockDim.x + threadIdx.x;
  int sel = i >> 16;
  const float* src = sel == 0 ? a : sel == 1 ? b : sel == 2 ? c : d;
  float4 v = reinterpret_cast<const float4*>(src)[i & ((1<<16)-1)];
  uint2 o;
  o.x = (uint32_t)f2bf(v.x) | ((uint32_t)f2bf(v.y) << 16);
  o.y = (uint32_t)f2bf(v.z) | ((uint32_t)f2bf(v.w) << 16);
  reinterpret_cast<uint2*>(out)[i] = o;
}

// ---------------- QKV projection GEMM, fused fp32->bf16 A staging ----------------
// z=0: Q (oscale=C2, MODE0) ; z=1: K (MODE0) ; z=2: V (MODE2 transposed out)
// 512 thr = 8 waves (4m x 2n), tile 128x128, BK=64. A: reg-stage fp32 -> cvt -> swizzled
// ds_write_b128 (write-late). W: global_load_lds with pre-swizzled source.
__global__ __launch_bounds__(512)
void k_gemm_qkv(const float* __restrict__ Xq, const float* __restrict__ Xk,
                const float* __restrict__ Xv, const u16* __restrict__ Wall,
                const float* __restrict__ bq, const float* __restrict__ bk,
                const float* __restrict__ bv,
                u16* __restrict__ Qp, u16* __restrict__ Kp, u16* __restrict__ Vtp)
{
  __shared__ __align__(16) u16 As[2][128*64];
  __shared__ __align__(16) u16 Bs[2][128*64];
  const int tid = threadIdx.x;
  const int w = tid >> 6, l = tid & 63;
  const int wm = w & 3, wn = w >> 2;
  const int m0 = blockIdx.x * 128, n0 = blockIdx.y * 128;
  const int z = blockIdx.z;
  const int srow = l >> 3, sslot = l & 7;

  const float* X = z == 0 ? Xq : (z == 1 ? Xk : Xv);
  const u16*   W = Wall + (size_t)z * 512 * 512;
  const float* bias = z == 0 ? bq : (z == 1 ? bk : bv);
  const float oscale = z == 0 ? C2 : 1.0f;

  const int arow = tid >> 2;            // 0..127
  const int ac   = (tid & 3) * 16;      // col base (of 64)

  f32x4 acc[2][4];
  #pragma unroll
  for (int i = 0; i < 2; i++)
    #pragma unroll
    for (int j = 0; j < 4; j++)
      #pragma unroll
      for (int r = 0; r < 4; r++) acc[i][j][r] = 0.f;

  float4 av[4];
  auto LOADA = [&](int kt){
    #pragma unroll
    for (int j = 0; j < 4; j++)
      av[j] = *reinterpret_cast<const float4*>(&X[(long)(m0 + arow)*D + kt + ac + j*4]);
  };
  auto WRITEA = [&](int buf){
    #pragma unroll
    for (int j2 = 0; j2 < 2; j2++){
      u32x4 p;
      p[0] = cvt_pk_bf16(av[2*j2].x,   av[2*j2].y);
      p[1] = cvt_pk_bf16(av[2*j2].z,   av[2*j2].w);
      p[2] = cvt_pk_bf16(av[2*j2+1].x, av[2*j2+1].y);
      p[3] = cvt_pk_bf16(av[2*j2+1].z, av[2*j2+1].w);
      int slot = ((ac >> 3) + j2) ^ (arow & 7);
      *reinterpret_cast<u32x4*>(&As[buf][arow*64 + slot*8]) = p;
    }
  };
  auto STAGEB = [&](int buf, int kt){
    #pragma unroll
    for (int i = 0; i < 2; i++){
      int r = w*16 + i*8 + srow;
      int scol = (sslot ^ (r & 7)) * 8;
      __builtin_amdgcn_global_load_lds(GPTR(W + (long)(n0 + r)*D + kt + scol),
                                       LPTR(&Bs[buf][(w*16 + i*8)*64]), 16, 0, 0);
    }
  };

  LOADA(0); STAGEB(0, 0);
  asm volatile("s_waitcnt vmcnt(0)" ::: "memory");
  WRITEA(0);
  __syncthreads();

  for (int t = 0; t < 8; t++){
    int buf = t & 1;
    if (t < 7){ STAGEB(buf ^ 1, (t+1)*64); LOADA((t+1)*64); }
    #pragma unroll
    for (int ks = 0; ks < 2; ks++){
      short8 af[2];
      #pragma unroll
      for (int mf = 0; mf < 2; mf++){
        int row = wm*32 + mf*16 + (l & 15);
        int cw = (ks*4 + (l >> 4)) ^ (row & 7);
        af[mf] = *reinterpret_cast<const short8*>(&As[buf][(row*8 + cw)*8]);
      }
      #pragma unroll
      for (int nf = 0; nf < 4; nf++){
        int row = wn*64 + nf*16 + (l & 15);
        int cw = (ks*4 + (l >> 4)) ^ (row & 7);
        short8 bf = *reinterpret_cast<const short8*>(&Bs[buf][(row*8 + cw)*8]);
        #pragma unroll
        for (int mf = 0; mf < 2; mf++)
          acc[mf][nf] = __builtin_amdgcn_mfma_f32_16x16x32_bf16(af[mf], bf, acc[mf][nf], 0, 0, 0);
      }
    }
    asm volatile("s_waitcnt vmcnt(0)" ::: "memory");
    if (t < 7) WRITEA(buf ^ 1);
    __syncthreads();
  }

  #pragma unroll
  for (int mf = 0; mf < 2; mf++){
    #pragma unroll
    for (int nf = 0; nf < 4; nf++){
      int n = n0 + wn*64 + nf*16 + (l & 15);
      float bi = bias[n];
      int h_ = n >> 6, d_ = n & 63;
      if (z == 2){
        int mb = m0 + wm*32 + mf*16 + (l >> 4)*4;
        int b_ = mb >> 11, s_ = mb & 2047;
        uint2 o;
        o.x = (uint32_t)f2bf(acc[mf][nf][0] + bi) | ((uint32_t)f2bf(acc[mf][nf][1] + bi) << 16);
        o.y = (uint32_t)f2bf(acc[mf][nf][2] + bi) | ((uint32_t)f2bf(acc[mf][nf][3] + bi) << 16);
        *reinterpret_cast<uint2*>(&Vtp[((long)((b_*8 + h_)*64 + d_))*2048 + s_]) = o;
      } else {
        u16* outp = z == 0 ? Qp : Kp;
        #pragma unroll
        for (int r = 0; r < 4; r++){
          int m = m0 + wm*32 + mf*16 + (l >> 4)*4 + r;
          int b_ = m >> 11, s_ = m & 2047;
          outp[((long)((b_*8 + h_)*2048 + s_))*64 + d_] = f2bf((acc[mf][nf][r] + bi)*oscale);
        }
      }
    }
  }
}

// ---------------- output GEMM: d_out[m][n] = sum_k AO[m][k]*Wo[n][k] + bias2[b][n] ----------------
__global__ __launch_bounds__(512)
void k_gemm_ao(const u16* __restrict__ A, const u16* __restrict__ W,
               const float* __restrict__ bias2, float* __restrict__ outp)
{
  __shared__ __align__(16) u16 As[2][128*64];
  __shared__ __align__(16) u16 Bs[2][128*64];
  const int tid = threadIdx.x;
  const int w = tid >> 6, l = tid & 63;
  const int wm = w & 3, wn = w >> 2;
  const int m0 = blockIdx.x * 128, n0 = blockIdx.y * 128;
  const int srow = l >> 3, sslot = l & 7;

  f32x4 acc[2][4];
  #pragma unroll
  for (int i = 0; i < 2; i++)
    #pragma unroll
    for (int j = 0; j < 4; j++)
      #pragma unroll
      for (int r = 0; r < 4; r++) acc[i][j][r] = 0.f;

  auto STAGE = [&](int buf, int kt){
    #pragma unroll
    for (int i = 0; i < 2; i++){
      int r = w*16 + i*8 + srow;
      int scol = (sslot ^ (r & 7)) * 8;
      int m = m0 + r, k = kt + scol;
      long ga = ((long)(((m >> 11)*8 + (k >> 6))*2048 + (m & 2047)))*64 + (k & 63);
      __builtin_amdgcn_global_load_lds(GPTR(A + ga), LPTR(&As[buf][(w*16 + i*8)*64]), 16, 0, 0);
      long gb = (long)(n0 + r)*D + kt + scol;
      __builtin_amdgcn_global_load_lds(GPTR(W + gb), LPTR(&Bs[buf][(w*16 + i*8)*64]), 16, 0, 0);
    }
  };

  STAGE(0, 0);
  asm volatile("s_waitcnt vmcnt(0)" ::: "memory");
  __builtin_amdgcn_s_barrier();
  FENCE;

  for (int kt = 0; kt < D; kt += 64){
    int buf = (kt >> 6) & 1;
    if (kt + 64 < D) STAGE(buf ^ 1, kt + 64);
    #pragma unroll
    for (int ks = 0; ks < 2; ks++){
      short8 af[2];
      #pragma unroll
      for (int mf = 0; mf < 2; mf++){
        int row = wm*32 + mf*16 + (l & 15);
        int cw = (ks*4 + (l >> 4)) ^ (row & 7);
        af[mf] = *reinterpret_cast<const short8*>(&As[buf][(row*8 + cw)*8]);
      }
      #pragma unroll
      for (int nf = 0; nf < 4; nf++){
        int row = wn*64 + nf*16 + (l & 15);
        int cw = (ks*4 + (l >> 4)) ^ (row & 7);
        short8 bf = *reinterpret_cast<const short8*>(&Bs[buf][(row*8 + cw)*8]);
        #pragma unroll
        for (int mf = 0; mf < 2; mf++)
          acc[mf][nf] = __builtin_amdgcn_mfma_f32_16x16x32_bf16(af[mf], bf, acc[mf][nf], 0, 0, 0);
      }
    }
    asm volatile("s_waitcnt vmcnt(0)" ::: "memory");
    __builtin_amdgcn_s_barrier();
    FENCE;
  }

  #pragma unroll
  for (int mf = 0; mf < 2; mf++)
    #pragma unroll
    for (int nf = 0; nf < 4; nf++){
      int n = n0 + wn*64 + nf*16 + (l & 15);
      float bi = bias2[(m0 >> 11)*512 + n];
      #pragma unroll
      for (int r = 0; r < 4; r++){
        int m = m0 + wm*32 + mf*16 + (l >> 4)*4 + r;
        outp[(long)m*D + n] = acc[mf][nf][r] + bi;
      }
    }
}

// ---------------- SV[bh][d] = sum_t Vt[bh][d][t] ----------------
__global__ __launch_bounds__(256)
void k_sumv(const u16* __restrict__ Vt, float* __restrict__ SV){
  const int w = threadIdx.x >> 6, l = threadIdx.x & 63;
  const int row = blockIdx.x*4 + w;
  const u16* src = Vt + (long)row * S;
  float s = 0.f;
  #pragma unroll
  for (int j = 0; j < 4; j++){
    short8 v = *reinterpret_cast<const short8*>(&src[j*512 + l*8]);
    #pragma unroll
    for (int e = 0; e < 8; e++)
      s += __uint_as_float(((uint32_t)(u16)v[e]) << 16);
  }
  #pragma unroll
  for (int m = 1; m < 64; m <<= 1) s += __shfl_xor(s, m, 64);
  if (l == 0) SV[row] = s;
}

// ---------------- bias2[b][n] = bo[n] + 0.5 * sum_k SV[b][k]*Wo[n][k] ----------------
__global__ __launch_bounds__(256)
void k_bias2(const float* __restrict__ SV, const float* __restrict__ Wo,
             const float* __restrict__ bo, float* __restrict__ bias2){
  const int w = threadIdx.x >> 6, l = threadIdx.x & 63;
  const int idx = blockIdx.x*4 + w;
  const int b = idx >> 9, n = idx & 511;
  float dot = 0.f;
  #pragma unroll
  for (int j = 0; j < 2; j++){
    float4 wv = *reinterpret_cast<const float4*>(&Wo[(long)n*512 + l*8 + j*4]);
    float4 sv = *reinterpret_cast<const float4*>(&SV[b*512 + l*8 + j*4]);
    dot += wv.x*sv.x + wv.y*sv.y + wv.z*sv.z + wv.w*sv.w;
  }
  #pragma unroll
  for (int m = 1; m < 64; m <<= 1) dot += __shfl_xor(dot, m, 64);
  if (l == 0) bias2[idx] = bo[n] + 0.5f * dot;
}

// ---------------- flash, 8 waves: groups 0/1 split even/odd K-tiles ----------------
// AO = 0.25 * softmax(K.(Q*C2)) V ; in-register P via cvt_pk + permlane32_swap
// zero16 loop-invariant MFMA C-operand kills per-tile acc zero-init; setprio around MFMA.
__global__ __launch_bounds__(512, 4)
void k_flash(const u16* __restrict__ Qp, const u16* __restrict__ Kp,
             const u16* __restrict__ Vt, u16* __restrict__ AO)
{
  __shared__ __align__(16) u16 Ks[2][2][64*64];   // [group][buf]
  __shared__ __align__(16) u16 Vs[2][2][64*64];
  const int tid = threadIdx.x, w = tid >> 6, l = tid & 63;
  const int g = w >> 2, w4 = w & 3;
  const int bh = blockIdx.x & 31, qt = blockIdx.x >> 5;
  const u16* Qb = Qp + (long)bh * S * DH;
  const int hi = l >> 5, ln = l & 31;
  const int srow = l >> 3, sslot = l & 7;

  short8 qfr[4];   // Q*C2 (scale folded in projection)
  #pragma unroll
  for (int c = 0; c < 4; c++){
    int row = qt*128 + w4*32 + ln;
    qfr[c] = *reinterpret_cast<const short8*>(&Qb[(long)row*DH + c*16 + hi*8]);
  }

  // lane-constant LDS read offsets (u16 units within Ks[g]/Vs[g])
  int koff[4], voff[8];
  #pragma unroll
  for (int c = 0; c < 4; c++)
    koff[c] = ln*64 + (((2*c + hi) ^ (ln & 7))*8);
  #pragma unroll
  for (int kf = 0; kf < 2; kf++)
    #pragma unroll
    for (int ch = 0; ch < 2; ch++)
      #pragma unroll
      for (int nf = 0; nf < 2; nf++)
        voff[kf*4 + ch*2 + nf] = (nf*32 + ln)*64 + ((((4*kf + 2*ch) + hi) ^ (ln & 7))*8);

  // staging pointers (advance per tile) + lane-constant source offsets
  const u16* kptr = Kp + (long)bh*S*DH + g*4096;
  const u16* vptr = Vt + (long)bh*DH*S + g*64;
  long ksrc[2], vsrc[2];
  #pragma unroll
  for (int i = 0; i < 2; i++){
    int r = w4*16 + i*8 + srow;
    int sc = (sslot ^ (r & 7))*8;
    ksrc[i] = (long)r*64 + sc;
    vsrc[i] = (long)r*S + sc;
  }

  auto STAGE = [&](int buf){
    #pragma unroll
    for (int i = 0; i < 2; i++){
      __builtin_amdgcn_global_load_lds(GPTR(kptr + ksrc[i]), LPTR(&Ks[g][buf][(w4*16 + i*8)*64]), 16, 0, 0);
      __builtin_amdgcn_global_load_lds(GPTR(vptr + vsrc[i]), LPTR(&Vs[g][buf][(w4*16 + i*8)*64]), 16, 0, 0);
    }
    kptr += 8192;   // 2 K-tiles (g-split stride)
    vptr += 128;    // 2 V-tiles of 64 cols
  };

  f32x16 zero16;
  #pragma unroll
  for (int r = 0; r < 16; r++) zero16[r] = 0.f;
  f32x16 oacc[2];
  #pragma unroll
  for (int j = 0; j < 2; j++)
    #pragma unroll
    for (int r = 0; r < 16; r++) oacc[j][r] = 0.f;
  float lsum = 0.f;

  STAGE(0);
  asm volatile("s_waitcnt vmcnt(0)" ::: "memory");
  __builtin_amdgcn_s_barrier();
  FENCE;

  const u16* KB = &Ks[g][0][0];
  const u16* VB = &Vs[g][0][0];

  for (int tp = 0; tp < 8; tp++){
    #pragma unroll
    for (int tt = 0; tt < 2; tt++){
      int t = tp*2 + tt;
      if (t < 15) STAGE(tt ^ 1);
      #pragma unroll
      for (int kf = 0; kf < 2; kf++){
        __builtin_amdgcn_s_setprio(1);
        short8 kf0 = *reinterpret_cast<const short8*>(KB + koff[0] + tt*4096 + kf*2048);
        f32x16 sacc = __builtin_amdgcn_mfma_f32_32x32x16_bf16(kf0, qfr[0], zero16, 0, 0, 0);
        #pragma unroll
        for (int c = 1; c < 4; c++){
          short8 kfrag = *reinterpret_cast<const short8*>(KB + koff[c] + tt*4096 + kf*2048);
          sacc = __builtin_amdgcn_mfma_f32_32x32x16_bf16(kfrag, qfr[c], sacc, 0, 0, 0);
        }
        __builtin_amdgcn_s_setprio(0);
        uint32_t pk[8];
        #pragma unroll
        for (int j = 0; j < 8; j++){
          float e0 = __builtin_amdgcn_exp2f(sacc[2*j]);
          float e1 = __builtin_amdgcn_exp2f(sacc[2*j+1]);
          lsum += e0 + e1;
          pk[j] = cvt_pk_bf16(e0, e1);
        }
        #pragma unroll
        for (int ch = 0; ch < 2; ch++){
          auto s1 = __builtin_amdgcn_permlane32_swap(pk[ch*4+0], pk[ch*4+2], false, false);
          auto s2 = __builtin_amdgcn_permlane32_swap(pk[ch*4+1], pk[ch*4+3], false, false);
          u32x4 av = { (uint32_t)s1[0], (uint32_t)s2[0], (uint32_t)s1[1], (uint32_t)s2[1] };
          short8 af = __builtin_bit_cast(short8, av);
          __builtin_amdgcn_s_setprio(1);
          #pragma unroll
          for (int nf = 0; nf < 2; nf++){
            short8 vfrag = *reinterpret_cast<const short8*>(VB + voff[kf*4 + ch*2 + nf] + tt*4096);
            oacc[nf] = __builtin_amdgcn_mfma_f32_32x32x16_bf16(af, vfrag, oacc[nf], 0, 0, 0);
          }
          __builtin_amdgcn_s_setprio(0);
        }
      }
      asm volatile("s_waitcnt vmcnt(0)" ::: "memory");
      __builtin_amdgcn_s_barrier();
      FENCE;
    }
  }

  // cross-group combine in LDS (tiles done; reuse Ks as 32KB f32 buffer)
  lsum += __shfl_xor(lsum, 32, 64);
  float* OB = (float*)Ks;
  float* LB = (float*)Vs;
  if (g == 1){
    #pragma unroll
    for (int r = 0; r < 16; r++){
      int qrow = (r & 3) + 8*(r >> 2) + 4*hi;
      #pragma unroll
      for (int nf = 0; nf < 2; nf++)
        OB[w4*2048 + qrow*64 + nf*32 + ln] = oacc[nf][r];
    }
    if (hi == 0) LB[w4*32 + ln] = lsum;
  }
  __syncthreads();
  if (g == 0){
    float l2 = LB[w4*32 + ln];
    float linv = 0.25f / (lsum + l2);   // valid for qrow = ln
    #pragma unroll
    for (int r = 0; r < 16; r++){
      int qrow = (r & 3) + 8*(r >> 2) + 4*hi;
      float sc = __shfl(linv, qrow, 64);
      int s_ = qt*128 + w4*32 + qrow;
      #pragma unroll
      for (int nf = 0; nf < 2; nf++){
        float o = oacc[nf][r] + OB[w4*2048 + qrow*64 + nf*32 + ln];
        AO[((long)bh*S + s_)*DH + nf*32 + ln] = f2bf(o * sc);
      }
    }
  }
}

// ---------------- launch ----------------
extern "C" void kernel_launch(void* const* d_in, const int* in_sizes, int n_in,
                              void* d_out, int out_size, void* d_ws, size_t ws_size,
                              hipStream_t stream)
{
  const float* query = (const float*)d_in[0];
  const float* key_  = (const float*)d_in[1];
  const float* value = (const float*)d_in[2];
  const float* Wq = (const float*)d_in[3];
  const float* bq = (const float*)d_in[4];
  const float* Wk = (const float*)d_in[5];
  const float* bk = (const float*)d_in[6];
  const float* Wv = (const float*)d_in[7];
  const float* bv = (const float*)d_in[8];
  const float* Wo = (const float*)d_in[9];
  const float* bo = (const float*)d_in[10];

  char* ws = (char*)d_ws;
  const size_t XSZ = (size_t)8192 * 512 * 2;   // 8 MiB
  const size_t WSZ = (size_t)512 * 512 * 2;    // 512 KiB
  u16* AO  = (u16*)(ws);
  u16* wqb = (u16*)(ws + XSZ);                 // wq|wk|wv|wo contiguous
  u16* wob = (u16*)(ws + XSZ + 3*WSZ);
  u16* Qp  = (u16*)(ws + XSZ + 4*WSZ);
  u16* Kp  = (u16*)(ws + 2*XSZ + 4*WSZ);
  u16* Vtp = (u16*)(ws + 3*XSZ + 4*WSZ);
  float* SV    = (float*)(ws + 4*XSZ + 4*WSZ);
  float* bias2 = (float*)(ws + 4*XSZ + 4*WSZ + 8192);

  k_cvtw<<<(4<<16)/256, 256, 0, stream>>>(Wq, Wk, Wv, Wo, wqb);

  dim3 gq(64, 4, 3);
  k_gemm_qkv<<<gq, 512, 0, stream>>>(query, key_, value, wqb, bq, bk, bv, Qp, Kp, Vtp);

  k_sumv <<<512, 256, 0, stream>>>(Vtp, SV);
  k_bias2<<<512, 256, 0, stream>>>(SV, Wo, bo, bias2);

  k_flash<<<512, 512, 0, stream>>>(Qp, Kp, Vtp, AO);

  dim3 gg(64, 4);
  k_gemm_ao<<<gg, 512, 0, stream>>>(AO, wob, bias2, (float*)d_out);
}

// Round 8
// 95.553 us; speedup vs baseline: 1.4833x; 1.0279x over previous
//
#include <hip/hip_runtime.h>
#include <stdint.h>
#include <math.h>

using u16    = unsigned short;
using short8 = __attribute__((ext_vector_type(8))) short;
using f32x4  = __attribute__((ext_vector_type(4))) float;
using f32x16 = __attribute__((ext_vector_type(16))) float;
using u32x4  = __attribute__((ext_vector_type(4))) uint32_t;

#define DEVI __device__ __forceinline__
#define FENCE asm volatile("" ::: "memory")
#define GPTR(p) ((const __attribute__((address_space(1))) uint32_t*)(p))
#define LPTR(p) ((__attribute__((address_space(3))) uint32_t*)(p))

static constexpr int S  = 2048;
static constexpr int D  = 512;
static constexpr int DH = 64;
// log2(e)/sqrt(512): folded into the Q projection output
static constexpr float C2 = 0.063763906f;

DEVI u16 f2bf(float f){
  uint32_t u = __float_as_uint(f);
  u = u + 0x7FFFu + ((u >> 16) & 1u);   // RNE
  return (u16)(u >> 16);
}

DEVI uint32_t cvt_pk_bf16(float a, float b){
  uint32_t d;
  asm("v_cvt_pk_bf16_f32 %0, %1, %2" : "=v"(d) : "v"(a), "v"(b));
  return d;
}

// ---------------- weight fp32 -> bf16 (wq|wk|wv|wo contiguous) ----------------
__global__ void k_cvtw(const float* __restrict__ a, const float* __restrict__ b,
                       const float* __restrict__ c, const float* __restrict__ d,
                       u16* __restrict__ out){
  int i = blockIdx.x * blockDim.x + threadIdx.x;
  int sel = i >> 16;
  const float* src = sel == 0 ? a : sel == 1 ? b : sel == 2 ? c : d;
  float4 v = reinterpret_cast<const float4*>(src)[i & ((1<<16)-1)];
  uint2 o;
  o.x = (uint32_t)f2bf(v.x) | ((uint32_t)f2bf(v.y) << 16);
  o.y = (uint32_t)f2bf(v.z) | ((uint32_t)f2bf(v.w) << 16);
  reinterpret_cast<uint2*>(out)[i] = o;
}

// ---------------- QKV projection GEMM, fused fp32->bf16 A staging ----------------
// z=0: Q (oscale=C2) ; z=1: K ; z=2: V (transposed out)
__global__ __launch_bounds__(512)
void k_gemm_qkv(const float* __restrict__ Xq, const float* __restrict__ Xk,
                const float* __restrict__ Xv, const u16* __restrict__ Wall,
                const float* __restrict__ bq, const float* __restrict__ bk,
                const float* __restrict__ bv,
                u16* __restrict__ Qp, u16* __restrict__ Kp, u16* __restrict__ Vtp)
{
  __shared__ __align__(16) u16 As[2][128*64];
  __shared__ __align__(16) u16 Bs[2][128*64];
  const int tid = threadIdx.x;
  const int w = tid >> 6, l = tid & 63;
  const int wm = w & 3, wn = w >> 2;
  const int m0 = blockIdx.x * 128, n0 = blockIdx.y * 128;
  const int z = blockIdx.z;
  const int srow = l >> 3, sslot = l & 7;

  const float* X = z == 0 ? Xq : (z == 1 ? Xk : Xv);
  const u16*   W = Wall + (size_t)z * 512 * 512;
  const float* bias = z == 0 ? bq : (z == 1 ? bk : bv);
  const float oscale = z == 0 ? C2 : 1.0f;

  const int arow = tid >> 2;            // 0..127
  const int ac   = (tid & 3) * 16;      // col base (of 64)

  f32x4 acc[2][4];
  #pragma unroll
  for (int i = 0; i < 2; i++)
    #pragma unroll
    for (int j = 0; j < 4; j++)
      #pragma unroll
      for (int r = 0; r < 4; r++) acc[i][j][r] = 0.f;

  float4 av[4];
  auto LOADA = [&](int kt){
    #pragma unroll
    for (int j = 0; j < 4; j++)
      av[j] = *reinterpret_cast<const float4*>(&X[(long)(m0 + arow)*D + kt + ac + j*4]);
  };
  auto WRITEA = [&](int buf){
    #pragma unroll
    for (int j2 = 0; j2 < 2; j2++){
      u32x4 p;
      p[0] = cvt_pk_bf16(av[2*j2].x,   av[2*j2].y);
      p[1] = cvt_pk_bf16(av[2*j2].z,   av[2*j2].w);
      p[2] = cvt_pk_bf16(av[2*j2+1].x, av[2*j2+1].y);
      p[3] = cvt_pk_bf16(av[2*j2+1].z, av[2*j2+1].w);
      int slot = ((ac >> 3) + j2) ^ (arow & 7);
      *reinterpret_cast<u32x4*>(&As[buf][arow*64 + slot*8]) = p;
    }
  };
  auto STAGEB = [&](int buf, int kt){
    #pragma unroll
    for (int i = 0; i < 2; i++){
      int r = w*16 + i*8 + srow;
      int scol = (sslot ^ (r & 7)) * 8;
      __builtin_amdgcn_global_load_lds(GPTR(W + (long)(n0 + r)*D + kt + scol),
                                       LPTR(&Bs[buf][(w*16 + i*8)*64]), 16, 0, 0);
    }
  };

  LOADA(0); STAGEB(0, 0);
  WRITEA(0);
  __syncthreads();

  for (int t = 0; t < 8; t++){
    int buf = t & 1;
    if (t < 7){ LOADA((t+1)*64); STAGEB(buf ^ 1, (t+1)*64); }
    #pragma unroll
    for (int ks = 0; ks < 2; ks++){
      short8 af[2];
      #pragma unroll
      for (int mf = 0; mf < 2; mf++){
        int row = wm*32 + mf*16 + (l & 15);
        int cw = (ks*4 + (l >> 4)) ^ (row & 7);
        af[mf] = *reinterpret_cast<const short8*>(&As[buf][(row*8 + cw)*8]);
      }
      #pragma unroll
      for (int nf = 0; nf < 4; nf++){
        int row = wn*64 + nf*16 + (l & 15);
        int cw = (ks*4 + (l >> 4)) ^ (row & 7);
        short8 bf = *reinterpret_cast<const short8*>(&Bs[buf][(row*8 + cw)*8]);
        #pragma unroll
        for (int mf = 0; mf < 2; mf++)
          acc[mf][nf] = __builtin_amdgcn_mfma_f32_16x16x32_bf16(af[mf], bf, acc[mf][nf], 0, 0, 0);
      }
    }
    if (t < 7) WRITEA(buf ^ 1);
    __syncthreads();
  }

  #pragma unroll
  for (int mf = 0; mf < 2; mf++){
    #pragma unroll
    for (int nf = 0; nf < 4; nf++){
      int n = n0 + wn*64 + nf*16 + (l & 15);
      float bi = bias[n];
      int h_ = n >> 6, d_ = n & 63;
      if (z == 2){
        int mb = m0 + wm*32 + mf*16 + (l >> 4)*4;
        int b_ = mb >> 11, s_ = mb & 2047;
        uint2 o;
        o.x = (uint32_t)f2bf(acc[mf][nf][0] + bi) | ((uint32_t)f2bf(acc[mf][nf][1] + bi) << 16);
        o.y = (uint32_t)f2bf(acc[mf][nf][2] + bi) | ((uint32_t)f2bf(acc[mf][nf][3] + bi) << 16);
        *reinterpret_cast<uint2*>(&Vtp[((long)((b_*8 + h_)*64 + d_))*2048 + s_]) = o;
      } else {
        u16* outp = z == 0 ? Qp : Kp;
        #pragma unroll
        for (int r = 0; r < 4; r++){
          int m = m0 + wm*32 + mf*16 + (l >> 4)*4 + r;
          int b_ = m >> 11, s_ = m & 2047;
          outp[((long)((b_*8 + h_)*2048 + s_))*64 + d_] = f2bf((acc[mf][nf][r] + bi)*oscale);
        }
      }
    }
  }
}

// ---------------- output GEMM: 3-buffer counted-vmcnt pipeline ----------------
__global__ __launch_bounds__(512)
void k_gemm_ao(const u16* __restrict__ A, const u16* __restrict__ W,
               const float* __restrict__ bias2, float* __restrict__ outp)
{
  __shared__ __align__(16) u16 As[3][128*64];
  __shared__ __align__(16) u16 Bs[3][128*64];
  const int tid = threadIdx.x;
  const int w = tid >> 6, l = tid & 63;
  const int wm = w & 3, wn = w >> 2;
  const int m0 = blockIdx.x * 128, n0 = blockIdx.y * 128;
  const int srow = l >> 3, sslot = l & 7;

  f32x4 acc[2][4];
  #pragma unroll
  for (int i = 0; i < 2; i++)
    #pragma unroll
    for (int j = 0; j < 4; j++)
      #pragma unroll
      for (int r = 0; r < 4; r++) acc[i][j][r] = 0.f;

  auto STAGE = [&](int buf, int kt){
    #pragma unroll
    for (int i = 0; i < 2; i++){
      int r = w*16 + i*8 + srow;
      int scol = (sslot ^ (r & 7)) * 8;
      int m = m0 + r, k = kt + scol;
      long ga = ((long)(((m >> 11)*8 + (k >> 6))*2048 + (m & 2047)))*64 + (k & 63);
      __builtin_amdgcn_global_load_lds(GPTR(A + ga), LPTR(&As[buf][(w*16 + i*8)*64]), 16, 0, 0);
      long gb = (long)(n0 + r)*D + kt + scol;
      __builtin_amdgcn_global_load_lds(GPTR(W + gb), LPTR(&Bs[buf][(w*16 + i*8)*64]), 16, 0, 0);
    }
  };

  STAGE(0, 0); STAGE(1, 64);
  asm volatile("s_waitcnt vmcnt(4)" ::: "memory");
  __builtin_amdgcn_s_barrier();
  FENCE;

  #pragma unroll
  for (int t = 0; t < 8; t++){
    const int buf = t % 3;
    if (t + 2 < 8) STAGE((t + 2) % 3, (t + 2)*64);
    #pragma unroll
    for (int ks = 0; ks < 2; ks++){
      short8 af[2];
      #pragma unroll
      for (int mf = 0; mf < 2; mf++){
        int row = wm*32 + mf*16 + (l & 15);
        int cw = (ks*4 + (l >> 4)) ^ (row & 7);
        af[mf] = *reinterpret_cast<const short8*>(&As[buf][(row*8 + cw)*8]);
      }
      #pragma unroll
      for (int nf = 0; nf < 4; nf++){
        int row = wn*64 + nf*16 + (l & 15);
        int cw = (ks*4 + (l >> 4)) ^ (row & 7);
        short8 bf = *reinterpret_cast<const short8*>(&Bs[buf][(row*8 + cw)*8]);
        #pragma unroll
        for (int mf = 0; mf < 2; mf++)
          acc[mf][nf] = __builtin_amdgcn_mfma_f32_16x16x32_bf16(af[mf], bf, acc[mf][nf], 0, 0, 0);
      }
    }
    if (t < 7){
      if (t < 6) asm volatile("s_waitcnt vmcnt(4)" ::: "memory");
      else       asm volatile("s_waitcnt vmcnt(0)" ::: "memory");
      __builtin_amdgcn_s_barrier();
      FENCE;
    }
  }

  #pragma unroll
  for (int mf = 0; mf < 2; mf++)
    #pragma unroll
    for (int nf = 0; nf < 4; nf++){
      int n = n0 + wn*64 + nf*16 + (l & 15);
      float bi = bias2[(m0 >> 11)*512 + n];
      #pragma unroll
      for (int r = 0; r < 4; r++){
        int m = m0 + wm*32 + mf*16 + (l >> 4)*4 + r;
        outp[(long)m*D + n] = acc[mf][nf][r] + bi;
      }
    }
}

// ---------------- SV[bh][d] = sum_t Vt[bh][d][t] ----------------
__global__ __launch_bounds__(256)
void k_sumv(const u16* __restrict__ Vt, float* __restrict__ SV){
  const int w = threadIdx.x >> 6, l = threadIdx.x & 63;
  const int row = blockIdx.x*4 + w;
  const u16* src = Vt + (long)row * S;
  float s = 0.f;
  #pragma unroll
  for (int j = 0; j < 4; j++){
    short8 v = *reinterpret_cast<const short8*>(&src[j*512 + l*8]);
    #pragma unroll
    for (int e = 0; e < 8; e++)
      s += __uint_as_float(((uint32_t)(u16)v[e]) << 16);
  }
  #pragma unroll
  for (int m = 1; m < 64; m <<= 1) s += __shfl_xor(s, m, 64);
  if (l == 0) SV[row] = s;
}

// ---------------- bias2[b][n] = bo[n] + 0.5 * sum_k SV[b][k]*Wo[n][k] ----------------
__global__ __launch_bounds__(256)
void k_bias2(const float* __restrict__ SV, const float* __restrict__ Wo,
             const float* __restrict__ bo, float* __restrict__ bias2){
  const int w = threadIdx.x >> 6, l = threadIdx.x & 63;
  const int idx = blockIdx.x*4 + w;
  const int b = idx >> 9, n = idx & 511;
  float dot = 0.f;
  #pragma unroll
  for (int j = 0; j < 2; j++){
    float4 wv = *reinterpret_cast<const float4*>(&Wo[(long)n*512 + l*8 + j*4]);
    float4 sv = *reinterpret_cast<const float4*>(&SV[b*512 + l*8 + j*4]);
    dot += wv.x*sv.x + wv.y*sv.y + wv.z*sv.z + wv.w*sv.w;
  }
  #pragma unroll
  for (int m = 1; m < 64; m <<= 1) dot += __shfl_xor(dot, m, 64);
  if (l == 0) bias2[idx] = bo[n] + 0.5f * dot;
}

// ---------------- flash: 4-buffer 32-key sub-tiles, counted vmcnt(4) ----------------
// AO = 0.25 * softmax(K.(Q*C2)) V ; groups 0/1 split even/odd 32-key tiles.
__global__ __launch_bounds__(512, 4)
void k_flash(const u16* __restrict__ Qp, const u16* __restrict__ Kp,
             const u16* __restrict__ Vt, u16* __restrict__ AO)
{
  __shared__ __align__(16) u16 Ks[2][4][32*64];   // [group][buf] 32 keys x 64 d
  __shared__ __align__(16) u16 Vs[2][4][64*32];   // [group][buf] 64 d x 32 keys
  const int tid = threadIdx.x, w = tid >> 6, l = tid & 63;
  const int g = w >> 2, w4 = w & 3;
  const int bh = blockIdx.x & 31, qt = blockIdx.x >> 5;
  const u16* Qb = Qp + (long)bh * S * DH;
  const int hi = l >> 5, ln = l & 31;

  short8 qfr[4];   // Q*C2 (scale folded in projection)
  #pragma unroll
  for (int c = 0; c < 4; c++){
    int row = qt*128 + w4*32 + ln;
    qfr[c] = *reinterpret_cast<const short8*>(&Qb[(long)row*DH + c*16 + hi*8]);
  }

  // lane-constant LDS read offsets (u16 units within one buf)
  int koff[4], voff[4];
  #pragma unroll
  for (int c = 0; c < 4; c++)
    koff[c] = ln*64 + (((2*c + hi) ^ ((ln ^ (ln >> 3)) & 7))*8);
  #pragma unroll
  for (int ch = 0; ch < 2; ch++)
    #pragma unroll
    for (int nf = 0; nf < 2; nf++){
      int row = nf*32 + ln;
      voff[ch*2 + nf] = row*32 + (((2*ch + hi) ^ ((row ^ (row >> 2)) & 3))*8);
    }

  // staging: lane-constant source offsets, pointers advance per tile
  const u16* kptr = Kp + (long)bh*S*DH + g*2048;   // group keys interleave by 32
  const u16* vptr = Vt + (long)bh*DH*S + g*32;
  const int rK = w4*8 + (l >> 3), sK = l & 7;
  const int rV = w4*16 + (l >> 2), sV = l & 3;
  const long ksrc = (long)rK*64 + ((sK ^ ((rK ^ (rK >> 3)) & 7))*8);
  const long vsrc = (long)rV*S  + ((sV ^ ((rV ^ (rV >> 2)) & 3))*8);

  auto STAGE = [&](int buf){
    __builtin_amdgcn_global_load_lds(GPTR(kptr + ksrc), LPTR(&Ks[g][buf][w4*512]), 16, 0, 0);
    __builtin_amdgcn_global_load_lds(GPTR(vptr + vsrc), LPTR(&Vs[g][buf][w4*512]), 16, 0, 0);
    kptr += 4096;   // next tile for this group (64 keys forward)
    vptr += 64;
  };

  f32x16 zero16;
  #pragma unroll
  for (int r = 0; r < 16; r++) zero16[r] = 0.f;
  f32x16 oacc[2];
  #pragma unroll
  for (int j = 0; j < 2; j++)
    #pragma unroll
    for (int r = 0; r < 16; r++) oacc[j][r] = 0.f;
  float lsum = 0.f;

  const u16* KB = &Ks[g][0][0];
  const u16* VB = &Vs[g][0][0];

  auto COMPUTE = [&](int buf){
    const u16* KT = KB + buf*2048;
    const u16* VT = VB + buf*2048;
    __builtin_amdgcn_s_setprio(1);
    short8 k0 = *reinterpret_cast<const short8*>(KT + koff[0]);
    f32x16 sacc = __builtin_amdgcn_mfma_f32_32x32x16_bf16(k0, qfr[0], zero16, 0, 0, 0);
    #pragma unroll
    for (int c = 1; c < 4; c++){
      short8 kfrag = *reinterpret_cast<const short8*>(KT + koff[c]);
      sacc = __builtin_amdgcn_mfma_f32_32x32x16_bf16(kfrag, qfr[c], sacc, 0, 0, 0);
    }
    __builtin_amdgcn_s_setprio(0);
    uint32_t pk[8];
    #pragma unroll
    for (int j = 0; j < 8; j++){
      float e0 = __builtin_amdgcn_exp2f(sacc[2*j]);
      float e1 = __builtin_amdgcn_exp2f(sacc[2*j+1]);
      lsum += e0 + e1;
      pk[j] = cvt_pk_bf16(e0, e1);
    }
    #pragma unroll
    for (int ch = 0; ch < 2; ch++){
      auto s1 = __builtin_amdgcn_permlane32_swap(pk[ch*4+0], pk[ch*4+2], false, false);
      auto s2 = __builtin_amdgcn_permlane32_swap(pk[ch*4+1], pk[ch*4+3], false, false);
      u32x4 av = { (uint32_t)s1[0], (uint32_t)s2[0], (uint32_t)s1[1], (uint32_t)s2[1] };
      short8 af = __builtin_bit_cast(short8, av);
      __builtin_amdgcn_s_setprio(1);
      #pragma unroll
      for (int nf = 0; nf < 2; nf++){
        short8 vfrag = *reinterpret_cast<const short8*>(VT + voff[ch*2 + nf]);
        oacc[nf] = __builtin_amdgcn_mfma_f32_32x32x16_bf16(af, vfrag, oacc[nf], 0, 0, 0);
      }
      __builtin_amdgcn_s_setprio(0);
    }
  };

  // prologue: depth-3 prefetch
  STAGE(0); STAGE(1); STAGE(2);
  asm volatile("s_waitcnt vmcnt(4)" ::: "memory");
  __builtin_amdgcn_s_barrier();
  FENCE;

  for (int tp = 0; tp < 7; tp++){
    #pragma unroll
    for (int tt = 0; tt < 4; tt++){
      STAGE((tt + 3) & 3);
      COMPUTE(tt);
      asm volatile("s_waitcnt vmcnt(4)" ::: "memory");
      __builtin_amdgcn_s_barrier();
      FENCE;
    }
  }
  // tail: t = 28..31
  STAGE(3);
  COMPUTE(0);
  asm volatile("s_waitcnt vmcnt(4)" ::: "memory");
  __builtin_amdgcn_s_barrier(); FENCE;
  COMPUTE(1);
  asm volatile("s_waitcnt vmcnt(2)" ::: "memory");
  __builtin_amdgcn_s_barrier(); FENCE;
  COMPUTE(2);
  asm volatile("s_waitcnt vmcnt(0)" ::: "memory");
  __builtin_amdgcn_s_barrier(); FENCE;
  COMPUTE(3);

  __syncthreads();   // all compute done before LDS is reused as f32 buffers

  // cross-group combine in LDS
  lsum += __shfl_xor(lsum, 32, 64);
  float* OB = (float*)Ks;    // 4 waves x 32 qrow x 64 d = 32 KB
  float* LB = (float*)Vs;
  if (g == 1){
    #pragma unroll
    for (int r = 0; r < 16; r++){
      int qrow = (r & 3) + 8*(r >> 2) + 4*hi;
      #pragma unroll
      for (int nf = 0; nf < 2; nf++)
        OB[w4*2048 + qrow*64 + nf*32 + ln] = oacc[nf][r];
    }
    if (hi == 0) LB[w4*32 + ln] = lsum;
  }
  __syncthreads();
  if (g == 0){
    float l2 = LB[w4*32 + ln];
    float linv = 0.25f / (lsum + l2);   // valid for qrow = ln
    #pragma unroll
    for (int r = 0; r < 16; r++){
      int qrow = (r & 3) + 8*(r >> 2) + 4*hi;
      float sc = __shfl(linv, qrow, 64);
      int s_ = qt*128 + w4*32 + qrow;
      #pragma unroll
      for (int nf = 0; nf < 2; nf++){
        float o = oacc[nf][r] + OB[w4*2048 + qrow*64 + nf*32 + ln];
        AO[((long)bh*S + s_)*DH + nf*32 + ln] = f2bf(o * sc);
      }
    }
  }
}

// ---------------- launch ----------------
extern "C" void kernel_launch(void* const* d_in, const int* in_sizes, int n_in,
                              void* d_out, int out_size, void* d_ws, size_t ws_size,
                              hipStream_t stream)
{
  const float* query = (const float*)d_in[0];
  const float* key_  = (const float*)d_in[1];
  const float* value = (const float*)d_in[2];
  const float* Wq = (const float*)d_in[3];
  const float* bq = (const float*)d_in[4];
  const float* Wk = (const float*)d_in[5];
  const float* bk = (const float*)d_in[6];
  const float* Wv = (const float*)d_in[7];
  const float* bv = (const float*)d_in[8];
  const float* Wo = (const float*)d_in[9];
  const float* bo = (const float*)d_in[10];

  char* ws = (char*)d_ws;
  const size_t XSZ = (size_t)8192 * 512 * 2;   // 8 MiB
  const size_t WSZ = (size_t)512 * 512 * 2;    // 512 KiB
  u16* AO  = (u16*)(ws);
  u16* wqb = (u16*)(ws + XSZ);                 // wq|wk|wv|wo contiguous
  u16* wob = (u16*)(ws + XSZ + 3*WSZ);
  u16* Qp  = (u16*)(ws + XSZ + 4*WSZ);
  u16* Kp  = (u16*)(ws + 2*XSZ + 4*WSZ);
  u16* Vtp = (u16*)(ws + 3*XSZ + 4*WSZ);
  float* SV    = (float*)(ws + 4*XSZ + 4*WSZ);
  float* bias2 = (float*)(ws + 4*XSZ + 4*WSZ + 8192);

  k_cvtw<<<(4<<16)/256, 256, 0, stream>>>(Wq, Wk, Wv, Wo, wqb);

  dim3 gq(64, 4, 3);
  k_gemm_qkv<<<gq, 512, 0, stream>>>(query, key_, value, wqb, bq, bk, bv, Qp, Kp, Vtp);

  k_sumv <<<512, 256, 0, stream>>>(Vtp, SV);
  k_bias2<<<512, 256, 0, stream>>>(SV, Wo, bo, bias2);

  k_flash<<<512, 512, 0, stream>>>(Qp, Kp, Vtp, AO);

  dim3 gg(64, 4);
  k_gemm_ao<<<gg, 512, 0, stream>>>(AO, wob, bias2, (float*)d_out);
}

// Round 9
// 90.087 us; speedup vs baseline: 1.5733x; 1.0607x over previous
//
#include <hip/hip_runtime.h>
#include <stdint.h>
#include <math.h>

using u16    = unsigned short;
using short8 = __attribute__((ext_vector_type(8))) short;
using f32x4  = __attribute__((ext_vector_type(4))) float;
using f32x16 = __attribute__((ext_vector_type(16))) float;
using u32x4  = __attribute__((ext_vector_type(4))) uint32_t;

#define DEVI __device__ __forceinline__
#define FENCE asm volatile("" ::: "memory")
#define GPTR(p) ((const __attribute__((address_space(1))) uint32_t*)(p))
#define LPTR(p) ((__attribute__((address_space(3))) uint32_t*)(p))

static constexpr int S  = 2048;
static constexpr int D  = 512;
static constexpr int DH = 64;
// log2(e)/sqrt(512): folded into the Q projection output
static constexpr float C2 = 0.063763906f;

DEVI u16 f2bf(float f){
  uint32_t u = __float_as_uint(f);
  u = u + 0x7FFFu + ((u >> 16) & 1u);   // RNE
  return (u16)(u >> 16);
}

DEVI uint32_t cvt_pk_bf16(float a, float b){
  uint32_t d;
  asm("v_cvt_pk_bf16_f32 %0, %1, %2" : "=v"(d) : "v"(a), "v"(b));
  return d;
}

// ---------------- weight fp32 -> bf16 (wq|wk|wv|wo contiguous) ----------------
__global__ void k_cvtw(const float* __restrict__ a, const float* __restrict__ b,
                       const float* __restrict__ c, const float* __restrict__ d,
                       u16* __restrict__ out){
  int i = blockIdx.x * blockDim.x + threadIdx.x;
  int sel = i >> 16;
  const float* src = sel == 0 ? a : sel == 1 ? b : sel == 2 ? c : d;
  float4 v = reinterpret_cast<const float4*>(src)[i & ((1<<16)-1)];
  uint2 o;
  o.x = (uint32_t)f2bf(v.x) | ((uint32_t)f2bf(v.y) << 16);
  o.y = (uint32_t)f2bf(v.z) | ((uint32_t)f2bf(v.w) << 16);
  reinterpret_cast<uint2*>(out)[i] = o;
}

// ---------------- QKV projection GEMM: depth-2 A register pipeline ----------------
// z=0: Q (oscale=C2) ; z=1: K ; z=2: V (transposed out)
__global__ __launch_bounds__(512)
void k_gemm_qkv(const float* __restrict__ Xq, const float* __restrict__ Xk,
                const float* __restrict__ Xv, const u16* __restrict__ Wall,
                const float* __restrict__ bq, const float* __restrict__ bk,
                const float* __restrict__ bv,
                u16* __restrict__ Qp, u16* __restrict__ Kp, u16* __restrict__ Vtp)
{
  __shared__ __align__(16) u16 As[2][128*64];
  __shared__ __align__(16) u16 Bs[2][128*64];
  const int tid = threadIdx.x;
  const int w = tid >> 6, l = tid & 63;
  const int wm = w & 3, wn = w >> 2;
  const int m0 = blockIdx.x * 128, n0 = blockIdx.y * 128;
  const int z = blockIdx.z;
  const int srow = l >> 3, sslot = l & 7;

  const float* X = z == 0 ? Xq : (z == 1 ? Xk : Xv);
  const u16*   W = Wall + (size_t)z * 512 * 512;
  const float* bias = z == 0 ? bq : (z == 1 ? bk : bv);
  const float oscale = z == 0 ? C2 : 1.0f;

  const int arow = tid >> 2;            // 0..127
  const int ac   = (tid & 3) * 16;      // col base (of 64)

  f32x4 acc[2][4];
  #pragma unroll
  for (int i = 0; i < 2; i++)
    #pragma unroll
    for (int j = 0; j < 4; j++)
      #pragma unroll
      for (int r = 0; r < 4; r++) acc[i][j][r] = 0.f;

  float4 av[2][4];
  auto LOADA = [&](int p, int kt){
    #pragma unroll
    for (int j = 0; j < 4; j++)
      av[p][j] = *reinterpret_cast<const float4*>(&X[(long)(m0 + arow)*D + kt + ac + j*4]);
  };
  auto WRITEA = [&](int buf, int p){
    #pragma unroll
    for (int j2 = 0; j2 < 2; j2++){
      u32x4 pkv;
      pkv[0] = cvt_pk_bf16(av[p][2*j2].x,   av[p][2*j2].y);
      pkv[1] = cvt_pk_bf16(av[p][2*j2].z,   av[p][2*j2].w);
      pkv[2] = cvt_pk_bf16(av[p][2*j2+1].x, av[p][2*j2+1].y);
      pkv[3] = cvt_pk_bf16(av[p][2*j2+1].z, av[p][2*j2+1].w);
      int slot = ((ac >> 3) + j2) ^ (arow & 7);
      *reinterpret_cast<u32x4*>(&As[buf][arow*64 + slot*8]) = pkv;
    }
  };
  auto STAGEB = [&](int buf, int kt){
    #pragma unroll
    for (int i = 0; i < 2; i++){
      int r = w*16 + i*8 + srow;
      int scol = (sslot ^ (r & 7)) * 8;
      __builtin_amdgcn_global_load_lds(GPTR(W + (long)(n0 + r)*D + kt + scol),
                                       LPTR(&Bs[buf][(w*16 + i*8)*64]), 16, 0, 0);
    }
  };

  // prologue: tile0 A -> LDS, tile1 A -> regs, tile0 B staged
  LOADA(0, 0);
  STAGEB(0, 0);
  WRITEA(0, 0);                 // compiler waits av[0]
  LOADA(1, 64);                 // tile1 A in flight across barrier
  asm volatile("s_waitcnt vmcnt(4) lgkmcnt(0)" ::: "memory");  // STAGEB(0) done, LOADA(1) in flight
  __builtin_amdgcn_s_barrier();
  FENCE;

  #pragma unroll
  for (int t = 0; t < 8; t++){
    const int buf = t & 1;
    if (t < 7) STAGEB(buf ^ 1, (t+1)*64);
    if (t < 6) LOADA(t & 1, (t+2)*64);      // av[t&1] held tile t (already in LDS)
    #pragma unroll
    for (int ks = 0; ks < 2; ks++){
      short8 af[2];
      #pragma unroll
      for (int mf = 0; mf < 2; mf++){
        int row = wm*32 + mf*16 + (l & 15);
        int cw = (ks*4 + (l >> 4)) ^ (row & 7);
        af[mf] = *reinterpret_cast<const short8*>(&As[buf][(row*8 + cw)*8]);
      }
      #pragma unroll
      for (int nf = 0; nf < 4; nf++){
        int row = wn*64 + nf*16 + (l & 15);
        int cw = (ks*4 + (l >> 4)) ^ (row & 7);
        short8 bf = *reinterpret_cast<const short8*>(&Bs[buf][(row*8 + cw)*8]);
        #pragma unroll
        for (int mf = 0; mf < 2; mf++)
          acc[mf][nf] = __builtin_amdgcn_mfma_f32_16x16x32_bf16(af[mf], bf, acc[mf][nf], 0, 0, 0);
      }
    }
    if (t < 7) WRITEA(buf ^ 1, (t+1) & 1);  // data loaded a full iter ago
    if (t < 6)      asm volatile("s_waitcnt vmcnt(4) lgkmcnt(0)" ::: "memory");
    else if (t == 6) asm volatile("s_waitcnt vmcnt(0) lgkmcnt(0)" ::: "memory");
    if (t < 7){ __builtin_amdgcn_s_barrier(); FENCE; }
  }

  #pragma unroll
  for (int mf = 0; mf < 2; mf++){
    #pragma unroll
    for (int nf = 0; nf < 4; nf++){
      int n = n0 + wn*64 + nf*16 + (l & 15);
      float bi = bias[n];
      int h_ = n >> 6, d_ = n & 63;
      if (z == 2){
        int mb = m0 + wm*32 + mf*16 + (l >> 4)*4;
        int b_ = mb >> 11, s_ = mb & 2047;
        uint2 o;
        o.x = (uint32_t)f2bf(acc[mf][nf][0] + bi) | ((uint32_t)f2bf(acc[mf][nf][1] + bi) << 16);
        o.y = (uint32_t)f2bf(acc[mf][nf][2] + bi) | ((uint32_t)f2bf(acc[mf][nf][3] + bi) << 16);
        *reinterpret_cast<uint2*>(&Vtp[((long)((b_*8 + h_)*64 + d_))*2048 + s_]) = o;
      } else {
        u16* outp = z == 0 ? Qp : Kp;
        #pragma unroll
        for (int r = 0; r < 4; r++){
          int m = m0 + wm*32 + mf*16 + (l >> 4)*4 + r;
          int b_ = m >> 11, s_ = m & 2047;
          outp[((long)((b_*8 + h_)*2048 + s_))*64 + d_] = f2bf((acc[mf][nf][r] + bi)*oscale);
        }
      }
    }
  }
}

// ---------------- output GEMM: 3-buffer counted-vmcnt pipeline ----------------
__global__ __launch_bounds__(512)
void k_gemm_ao(const u16* __restrict__ A, const u16* __restrict__ W,
               const float* __restrict__ bias2, float* __restrict__ outp)
{
  __shared__ __align__(16) u16 As[3][128*64];
  __shared__ __align__(16) u16 Bs[3][128*64];
  const int tid = threadIdx.x;
  const int w = tid >> 6, l = tid & 63;
  const int wm = w & 3, wn = w >> 2;
  const int m0 = blockIdx.x * 128, n0 = blockIdx.y * 128;
  const int srow = l >> 3, sslot = l & 7;

  f32x4 acc[2][4];
  #pragma unroll
  for (int i = 0; i < 2; i++)
    #pragma unroll
    for (int j = 0; j < 4; j++)
      #pragma unroll
      for (int r = 0; r < 4; r++) acc[i][j][r] = 0.f;

  auto STAGE = [&](int buf, int kt){
    #pragma unroll
    for (int i = 0; i < 2; i++){
      int r = w*16 + i*8 + srow;
      int scol = (sslot ^ (r & 7)) * 8;
      int m = m0 + r, k = kt + scol;
      long ga = ((long)(((m >> 11)*8 + (k >> 6))*2048 + (m & 2047)))*64 + (k & 63);
      __builtin_amdgcn_global_load_lds(GPTR(A + ga), LPTR(&As[buf][(w*16 + i*8)*64]), 16, 0, 0);
      long gb = (long)(n0 + r)*D + kt + scol;
      __builtin_amdgcn_global_load_lds(GPTR(W + gb), LPTR(&Bs[buf][(w*16 + i*8)*64]), 16, 0, 0);
    }
  };

  STAGE(0, 0); STAGE(1, 64);
  asm volatile("s_waitcnt vmcnt(4)" ::: "memory");
  __builtin_amdgcn_s_barrier();
  FENCE;

  #pragma unroll
  for (int t = 0; t < 8; t++){
    const int buf = t % 3;
    if (t + 2 < 8) STAGE((t + 2) % 3, (t + 2)*64);
    #pragma unroll
    for (int ks = 0; ks < 2; ks++){
      short8 af[2];
      #pragma unroll
      for (int mf = 0; mf < 2; mf++){
        int row = wm*32 + mf*16 + (l & 15);
        int cw = (ks*4 + (l >> 4)) ^ (row & 7);
        af[mf] = *reinterpret_cast<const short8*>(&As[buf][(row*8 + cw)*8]);
      }
      #pragma unroll
      for (int nf = 0; nf < 4; nf++){
        int row = wn*64 + nf*16 + (l & 15);
        int cw = (ks*4 + (l >> 4)) ^ (row & 7);
        short8 bf = *reinterpret_cast<const short8*>(&Bs[buf][(row*8 + cw)*8]);
        #pragma unroll
        for (int mf = 0; mf < 2; mf++)
          acc[mf][nf] = __builtin_amdgcn_mfma_f32_16x16x32_bf16(af[mf], bf, acc[mf][nf], 0, 0, 0);
      }
    }
    if (t < 7){
      if (t < 6) asm volatile("s_waitcnt vmcnt(4)" ::: "memory");
      else       asm volatile("s_waitcnt vmcnt(0)" ::: "memory");
      __builtin_amdgcn_s_barrier();
      FENCE;
    }
  }

  #pragma unroll
  for (int mf = 0; mf < 2; mf++)
    #pragma unroll
    for (int nf = 0; nf < 4; nf++){
      int n = n0 + wn*64 + nf*16 + (l & 15);
      float bi = bias2[(m0 >> 11)*512 + n];
      #pragma unroll
      for (int r = 0; r < 4; r++){
        int m = m0 + wm*32 + mf*16 + (l >> 4)*4 + r;
        outp[(long)m*D + n] = acc[mf][nf][r] + bi;
      }
    }
}

// ---------------- SV[bh][d] = sum_t Vt[bh][d][t] ----------------
__global__ __launch_bounds__(256)
void k_sumv(const u16* __restrict__ Vt, float* __restrict__ SV){
  const int w = threadIdx.x >> 6, l = threadIdx.x & 63;
  const int row = blockIdx.x*4 + w;
  const u16* src = Vt + (long)row * S;
  float s = 0.f;
  #pragma unroll
  for (int j = 0; j < 4; j++){
    short8 v = *reinterpret_cast<const short8*>(&src[j*512 + l*8]);
    #pragma unroll
    for (int e = 0; e < 8; e++)
      s += __uint_as_float(((uint32_t)(u16)v[e]) << 16);
  }
  #pragma unroll
  for (int m = 1; m < 64; m <<= 1) s += __shfl_xor(s, m, 64);
  if (l == 0) SV[row] = s;
}

// ---------------- bias2[b][n] = bo[n] + 0.5 * sum_k SV[b][k]*Wo[n][k] ----------------
__global__ __launch_bounds__(256)
void k_bias2(const float* __restrict__ SV, const float* __restrict__ Wo,
             const float* __restrict__ bo, float* __restrict__ bias2){
  const int w = threadIdx.x >> 6, l = threadIdx.x & 63;
  const int idx = blockIdx.x*4 + w;
  const int b = idx >> 9, n = idx & 511;
  float dot = 0.f;
  #pragma unroll
  for (int j = 0; j < 2; j++){
    float4 wv = *reinterpret_cast<const float4*>(&Wo[(long)n*512 + l*8 + j*4]);
    float4 sv = *reinterpret_cast<const float4*>(&SV[b*512 + l*8 + j*4]);
    dot += wv.x*sv.x + wv.y*sv.y + wv.z*sv.z + wv.w*sv.w;
  }
  #pragma unroll
  for (int m = 1; m < 64; m <<= 1) dot += __shfl_xor(dot, m, 64);
  if (l == 0) bias2[idx] = bo[n] + 0.5f * dot;
}

// ---------------- flash: 64 q-rows/wave (halved LDS read amplification) ----------------
// AO = 0.25 * softmax(K.(Q*C2)) V ; 256 blocks = bh(32, fastest) x qt(8 of 256 rows)
// 8 waves: 4 q-waves x 2 key-groups; 4-buffer 32-key tiles, counted vmcnt(4).
__global__ __launch_bounds__(512, 2)
void k_flash(const u16* __restrict__ Qp, const u16* __restrict__ Kp,
             const u16* __restrict__ Vt, u16* __restrict__ AO)
{
  __shared__ __align__(16) u16 Ks[2][4][32*64];   // [group][buf] 32 keys x 64 d
  __shared__ __align__(16) u16 Vs[2][4][64*32];   // [group][buf] 64 d x 32 keys
  const int tid = threadIdx.x, w = tid >> 6, l = tid & 63;
  const int g = w >> 2, w4 = w & 3;
  const int bh = blockIdx.x & 31, qt = blockIdx.x >> 5;   // qt 0..7
  const u16* Qb = Qp + (long)bh * S * DH;
  const int hi = l >> 5, ln = l & 31;

  short8 qfr[2][4];   // 2 q-halves x 4 k-chunks (Q*C2 folded in projection)
  #pragma unroll
  for (int qh = 0; qh < 2; qh++)
    #pragma unroll
    for (int c = 0; c < 4; c++){
      int row = qt*256 + w4*64 + qh*32 + ln;
      qfr[qh][c] = *reinterpret_cast<const short8*>(&Qb[(long)row*DH + c*16 + hi*8]);
    }

  // lane-constant LDS read offsets (u16 units within one buf)
  int koff[4], voff[4];
  #pragma unroll
  for (int c = 0; c < 4; c++)
    koff[c] = ln*64 + (((2*c + hi) ^ ((ln ^ (ln >> 3)) & 7))*8);
  #pragma unroll
  for (int ch = 0; ch < 2; ch++)
    #pragma unroll
    for (int nf = 0; nf < 2; nf++){
      int row = nf*32 + ln;
      voff[ch*2 + nf] = row*32 + (((2*ch + hi) ^ ((row ^ (row >> 2)) & 3))*8);
    }

  // staging: lane-constant source offsets, pointers advance per tile
  const u16* kptr = Kp + (long)bh*S*DH + g*2048;
  const u16* vptr = Vt + (long)bh*DH*S + g*32;
  const int rK = w4*8 + (l >> 3), sK = l & 7;
  const int rV = w4*16 + (l >> 2), sV = l & 3;
  const long ksrc = (long)rK*64 + ((sK ^ ((rK ^ (rK >> 3)) & 7))*8);
  const long vsrc = (long)rV*S  + ((sV ^ ((rV ^ (rV >> 2)) & 3))*8);

  auto STAGE = [&](int buf){
    __builtin_amdgcn_global_load_lds(GPTR(kptr + ksrc), LPTR(&Ks[g][buf][w4*512]), 16, 0, 0);
    __builtin_amdgcn_global_load_lds(GPTR(vptr + vsrc), LPTR(&Vs[g][buf][w4*512]), 16, 0, 0);
    kptr += 4096;
    vptr += 64;
  };

  f32x16 zero16;
  #pragma unroll
  for (int r = 0; r < 16; r++) zero16[r] = 0.f;
  f32x16 oacc[2][2];   // [qh][nf]
  #pragma unroll
  for (int qh = 0; qh < 2; qh++)
    #pragma unroll
    for (int j = 0; j < 2; j++)
      #pragma unroll
      for (int r = 0; r < 16; r++) oacc[qh][j][r] = 0.f;
  float lsum[2] = {0.f, 0.f};

  const u16* KB = &Ks[g][0][0];
  const u16* VB = &Vs[g][0][0];

  auto COMPUTE = [&](int buf){
    const u16* KT = KB + buf*2048;
    const u16* VT = VB + buf*2048;
    short8 kfr[4];
    #pragma unroll
    for (int c = 0; c < 4; c++)
      kfr[c] = *reinterpret_cast<const short8*>(KT + koff[c]);
    __builtin_amdgcn_s_setprio(1);
    f32x16 sacc[2];
    #pragma unroll
    for (int qh = 0; qh < 2; qh++){
      sacc[qh] = __builtin_amdgcn_mfma_f32_32x32x16_bf16(kfr[0], qfr[qh][0], zero16, 0, 0, 0);
      #pragma unroll
      for (int c = 1; c < 4; c++)
        sacc[qh] = __builtin_amdgcn_mfma_f32_32x32x16_bf16(kfr[c], qfr[qh][c], sacc[qh], 0, 0, 0);
    }
    __builtin_amdgcn_s_setprio(0);
    uint32_t pk[2][8];
    #pragma unroll
    for (int qh = 0; qh < 2; qh++)
      #pragma unroll
      for (int j = 0; j < 8; j++){
        float e0 = __builtin_amdgcn_exp2f(sacc[qh][2*j]);
        float e1 = __builtin_amdgcn_exp2f(sacc[qh][2*j+1]);
        lsum[qh] += e0 + e1;
        pk[qh][j] = cvt_pk_bf16(e0, e1);
      }
    #pragma unroll
    for (int ch = 0; ch < 2; ch++){
      short8 af[2];
      #pragma unroll
      for (int qh = 0; qh < 2; qh++){
        auto s1 = __builtin_amdgcn_permlane32_swap(pk[qh][ch*4+0], pk[qh][ch*4+2], false, false);
        auto s2 = __builtin_amdgcn_permlane32_swap(pk[qh][ch*4+1], pk[qh][ch*4+3], false, false);
        u32x4 avv = { (uint32_t)s1[0], (uint32_t)s2[0], (uint32_t)s1[1], (uint32_t)s2[1] };
        af[qh] = __builtin_bit_cast(short8, avv);
      }
      __builtin_amdgcn_s_setprio(1);
      #pragma unroll
      for (int nf = 0; nf < 2; nf++){
        short8 vfrag = *reinterpret_cast<const short8*>(VT + voff[ch*2 + nf]);
        #pragma unroll
        for (int qh = 0; qh < 2; qh++)
          oacc[qh][nf] = __builtin_amdgcn_mfma_f32_32x32x16_bf16(af[qh], vfrag, oacc[qh][nf], 0, 0, 0);
      }
      __builtin_amdgcn_s_setprio(0);
    }
  };

  // prologue: depth-3 prefetch
  STAGE(0); STAGE(1); STAGE(2);
  asm volatile("s_waitcnt vmcnt(4)" ::: "memory");
  __builtin_amdgcn_s_barrier();
  FENCE;

  for (int tp = 0; tp < 7; tp++){
    #pragma unroll
    for (int tt = 0; tt < 4; tt++){
      STAGE((tt + 3) & 3);
      COMPUTE(tt);
      asm volatile("s_waitcnt vmcnt(4)" ::: "memory");
      __builtin_amdgcn_s_barrier();
      FENCE;
    }
  }
  // tail: last 4 tiles
  STAGE(3);
  COMPUTE(0);
  asm volatile("s_waitcnt vmcnt(4)" ::: "memory");
  __builtin_amdgcn_s_barrier(); FENCE;
  COMPUTE(1);
  asm volatile("s_waitcnt vmcnt(2)" ::: "memory");
  __builtin_amdgcn_s_barrier(); FENCE;
  COMPUTE(2);
  asm volatile("s_waitcnt vmcnt(0)" ::: "memory");
  __builtin_amdgcn_s_barrier(); FENCE;
  COMPUTE(3);

  __syncthreads();   // all compute done before LDS reuse

  // combine groups: lsum halves first
  lsum[0] += __shfl_xor(lsum[0], 32, 64);
  lsum[1] += __shfl_xor(lsum[1], 32, 64);

  float* OB = (float*)Ks;    // 4 waves x 32 qrow x 64 d = 32 KB
  float* LB = (float*)Vs;

  #pragma unroll
  for (int qh = 0; qh < 2; qh++){
    if (g == 1){
      #pragma unroll
      for (int r = 0; r < 16; r++){
        int qrow = (r & 3) + 8*(r >> 2) + 4*hi;
        #pragma unroll
        for (int nf = 0; nf < 2; nf++)
          OB[w4*2048 + qrow*64 + nf*32 + ln] = oacc[qh][nf][r];
      }
      if (hi == 0) LB[w4*32 + ln] = lsum[qh];
    }
    __syncthreads();
    if (g == 0){
      float lt = lsum[qh] + LB[w4*32 + ln];
      float linv = 0.25f / lt;              // valid for qrow = ln
      #pragma unroll
      for (int r = 0; r < 16; r++){
        int qrow = (r & 3) + 8*(r >> 2) + 4*hi;
        float sc = __shfl(linv, qrow, 64);
        int s_ = qt*256 + w4*64 + qh*32 + qrow;
        #pragma unroll
        for (int nf = 0; nf < 2; nf++){
          float o = oacc[qh][nf][r] + OB[w4*2048 + qrow*64 + nf*32 + ln];
          AO[((long)bh*S + s_)*DH + nf*32 + ln] = f2bf(o * sc);
        }
      }
    }
    __syncthreads();
  }
}

// ---------------- launch ----------------
extern "C" void kernel_launch(void* const* d_in, const int* in_sizes, int n_in,
                              void* d_out, int out_size, void* d_ws, size_t ws_size,
                              hipStream_t stream)
{
  const float* query = (const float*)d_in[0];
  const float* key_  = (const float*)d_in[1];
  const float* value = (const float*)d_in[2];
  const float* Wq = (const float*)d_in[3];
  const float* bq = (const float*)d_in[4];
  const float* Wk = (const float*)d_in[5];
  const float* bk = (const float*)d_in[6];
  const float* Wv = (const float*)d_in[7];
  const float* bv = (const float*)d_in[8];
  const float* Wo = (const float*)d_in[9];
  const float* bo = (const float*)d_in[10];

  char* ws = (char*)d_ws;
  const size_t XSZ = (size_t)8192 * 512 * 2;   // 8 MiB
  const size_t WSZ = (size_t)512 * 512 * 2;    // 512 KiB
  u16* AO  = (u16*)(ws);
  u16* wqb = (u16*)(ws + XSZ);                 // wq|wk|wv|wo contiguous
  u16* wob = (u16*)(ws + XSZ + 3*WSZ);
  u16* Qp  = (u16*)(ws + XSZ + 4*WSZ);
  u16* Kp  = (u16*)(ws + 2*XSZ + 4*WSZ);
  u16* Vtp = (u16*)(ws + 3*XSZ + 4*WSZ);
  float* SV    = (float*)(ws + 4*XSZ + 4*WSZ);
  float* bias2 = (float*)(ws + 4*XSZ + 4*WSZ + 8192);

  k_cvtw<<<(4<<16)/256, 256, 0, stream>>>(Wq, Wk, Wv, Wo, wqb);

  dim3 gq(64, 4, 3);
  k_gemm_qkv<<<gq, 512, 0, stream>>>(query, key_, value, wqb, bq, bk, bv, Qp, Kp, Vtp);

  k_sumv <<<512, 256, 0, stream>>>(Vtp, SV);
  k_bias2<<<512, 256, 0, stream>>>(SV, Wo, bo, bias2);

  k_flash<<<256, 512, 0, stream>>>(Qp, Kp, Vtp, AO);

  dim3 gg(64, 4);
  k_gemm_ao<<<gg, 512, 0, stream>>>(AO, wob, bias2, (float*)d_out);
}